// Round 7
// baseline (609.002 us; speedup 1.0000x reference)
//
#include <hip/hip_runtime.h>
#include <hip/hip_bf16.h>
#include <hip/hip_cooperative_groups.h>

namespace cg = cooperative_groups;

// Shapes: B=16, S=1024, E=64, H=8, d=8, INPUT_DIM=310
// local mask: |i-j|<=5 (11 keys); sparse mask: j%3==0 or i==j (342 keys + diag)
//
// R17 = R16 bodies merged into ONE cooperative kernel (grid.sync between
// phases). 1024 blocks x 256 thr, __launch_bounds__(256,4) => 4 blocks/CU
// co-resident. Fallback to the 4-dispatch R16 pipeline if cooperative launch
// is rejected. Phase bodies verbatim R16 (factored into __device__ fns).
//  phase 1: prep (grid-stride over 423936 items)
//  phase 2: proj+qkv GEMM (block = one 16-row tile)
//  phase 3: attn (2560 units, grid-stride)
//  phase 4: fuse GEMM + score (512 units) + cnt-based finalize

typedef __attribute__((ext_vector_type(8))) short short8;
typedef __attribute__((ext_vector_type(4))) float float4v;

#define INV_SQRT8 0.3535533905932738f

__device__ __forceinline__ float4 ld4(const float* p) { return *(const float4*)p; }

__device__ __forceinline__ float4 f4fma(float s, float4 w, float4 a) {
  a.x = fmaf(s, w.x, a.x); a.y = fmaf(s, w.y, a.y);
  a.z = fmaf(s, w.z, a.z); a.w = fmaf(s, w.w, a.w);
  return a;
}

__device__ __forceinline__ short f2bf(float x) {
  __hip_bfloat16 b = __float2bfloat16(x);
  unsigned short u; __builtin_memcpy(&u, &b, 2);
  return (short)u;
}
__device__ __forceinline__ float bf2f(short s) {
  return __uint_as_float(((unsigned)(unsigned short)s) << 16);
}
// fp32 -> (bf16 hi, bf16 lo); lo = x - hi exact in fp32.
__device__ __forceinline__ void bsplit(float x, short& h, short& l) {
  h = f2bf(x);
  l = f2bf(x - bf2f(h));
}

// ================= phase 1: prep item =================
__device__ __forceinline__ void prep_item(
    unsigned idx,
    const float* PW, const float* LIW, const float* GIW, const float* FW,
    const float* LOW, const float* GOW, const float* LOB, const float* GOB,
    const float* FB,
    short* wb, float* bc, float* numden, short* VTh, short* VTl)
{
  if (idx < 53248u) {
    float v; unsigned ho, lo_;
    if (idx < 20480u) {           // proj, padded K 310->320
      unsigned r = idx / 320u, k = idx - r * 320u;
      v = (k < 310u) ? PW[r * 310u + k] : 0.f;
      ho = 0u + idx; lo_ = 20480u + idx;
    } else if (idx < 32768u) {    // loc_in
      unsigned i = idx - 20480u; v = LIW[i]; ho = 40960u + i; lo_ = 53248u + i;
    } else if (idx < 45056u) {    // glob_in
      unsigned i = idx - 32768u; v = GIW[i]; ho = 65536u + i; lo_ = 77824u + i;
    } else {                      // fused fusion weight W12[n][k]
      unsigned i = idx - 45056u;
      unsigned n = i >> 7, k = i & 127u;
      float s = 0.f;
      if (k < 64u) {
        for (int e = 0; e < 64; e++) s += FW[n * 128 + e] * LOW[e * 64 + k];
      } else {
        for (int e = 0; e < 64; e++) s += FW[n * 128 + 64 + e] * GOW[e * 64 + (k - 64u)];
      }
      v = s; ho = 90112u + i; lo_ = 98304u + i;
    }
    short h, l; bsplit(v, h, l);
    wb[ho] = h; wb[lo_] = l;
    if (idx < 64u) {
      float b = FB[idx];
      for (int e = 0; e < 64; e++)
        b += LOB[e] * FW[idx * 128 + e] + GOB[e] * FW[idx * 128 + 64 + e];
      bc[idx] = b;
    }
    if (idx < 1041u) numden[idx] = 0.f;   // num[1024] + den[16] + cnt
  } else {
    unsigned t = idx - 53248u;
    if (t < 370688u) {
      unsigned pos; short hv = 0;
      if (t < 360448u) {                // n in [8,16): ones row / zeros, 128 bh
        unsigned bh = t / 2816u;        // 8*352
        unsigned rem = t - bh * 2816u;
        unsigned n8 = rem / 352u;
        unsigned kk = rem - n8 * 352u;
        pos = (bh * 16u + 8u + n8) * 352u + kk;
        if (n8 == 0u) hv = (short)0x3F80;   // bf16(1.0)
      } else {                          // n<8, kk in [342,352): zero pad
        unsigned t2 = t - 360448u;      // < 10240
        unsigned bh = t2 / 80u;
        unsigned rem = t2 - bh * 80u;
        unsigned n = rem / 10u;
        unsigned kk = 342u + (rem - n * 10u);
        pos = (bh * 16u + n) * 352u + kk;
      }
      VTh[pos] = hv; VTl[pos] = 0;
    }
  }
}

// ================= phase 2: proj + qkv for one 16-row tile =================
__device__ __forceinline__ void proj_qkv_tile(
    int m0, int tid,
    short XPH[16][72], short XPL[16][72],
    const float* X,
    const short* PWh, const short* PWl, const float* pb,
    const short* LWh, const short* LWl,
    const short* GWh, const short* GWl,
    const float* lb, const float* gb,
    float* qkv_l, float* qkv_g,
    short* KH, short* KL, short* VTh, short* VTl)
{
  const int lane = tid & 63;
  const int w = tid >> 6;
  const int q = lane >> 4, r = lane & 15;

  // ---- phase A: proj col-frag g = w
  float4v accp;
  {
    float bv = pb[w * 16 + r];
    float4v t = {bv, bv, bv, bv};
    accp = t;
  }
  const float* arow = X + (size_t)(m0 + r) * 310;
  #pragma unroll
  for (int ks = 0; ks < 10; ks++) {
    const int k0 = ks * 32 + q * 8;
    float av[8];
    if (ks < 9) {
      const float* ap = arow + k0;
      #pragma unroll
      for (int t = 0; t < 4; t++) {
        float2 f = *(const float2*)(ap + t * 2);
        av[t*2] = f.x; av[t*2+1] = f.y;
      }
    } else {
      #pragma unroll
      for (int j = 0; j < 8; j++) {
        int kidx = k0 + j;
        av[j] = (kidx < 310) ? arow[kidx] : 0.f;
      }
    }
    short8 ah, al;
    #pragma unroll
    for (int i = 0; i < 8; i++) { short h, l; bsplit(av[i], h, l); ah[i]=h; al[i]=l; }
    short8 bh = *(const short8*)(PWh + (size_t)(w * 16 + r) * 320 + k0);
    short8 bl = *(const short8*)(PWl + (size_t)(w * 16 + r) * 320 + k0);
    accp = __builtin_amdgcn_mfma_f32_16x16x32_bf16(al, bh, accp, 0, 0, 0);
    accp = __builtin_amdgcn_mfma_f32_16x16x32_bf16(ah, bl, accp, 0, 0, 0);
    accp = __builtin_amdgcn_mfma_f32_16x16x32_bf16(ah, bh, accp, 0, 0, 0);
  }
  #pragma unroll
  for (int e = 0; e < 4; e++) {
    short h, l; bsplit(accp[e], h, l);
    XPH[q * 4 + e][w * 16 + r] = h;
    XPL[q * 4 + e][w * 16 + r] = l;
  }
  __syncthreads();

  // ---- phase B: branch br, frag half hf
  const int br = w >> 1, hf = w & 1;
  const short* Wh = br ? GWh : LWh;
  const short* Wl = br ? GWl : LWl;
  const float* bb = br ? gb : lb;
  float* qkv = br ? qkv_g : qkv_l;

  float4v acc[6];
  #pragma unroll
  for (int j = 0; j < 6; j++) {
    float bv = bb[(hf * 6 + j) * 16 + r];
    float4v t = {bv, bv, bv, bv};
    acc[j] = t;
  }
  #pragma unroll
  for (int ks = 0; ks < 2; ks++) {
    const int k0 = ks * 32 + q * 8;
    short8 ah = *(const short8*)&XPH[r][k0];
    short8 al = *(const short8*)&XPL[r][k0];
    #pragma unroll
    for (int j = 0; j < 6; j++) {
      const int nf = hf * 6 + j;
      short8 bh = *(const short8*)(Wh + (size_t)(nf * 16 + r) * 64 + k0);
      short8 bl = *(const short8*)(Wl + (size_t)(nf * 16 + r) * 64 + k0);
      acc[j] = __builtin_amdgcn_mfma_f32_16x16x32_bf16(al, bh, acc[j], 0, 0, 0);
      acc[j] = __builtin_amdgcn_mfma_f32_16x16x32_bf16(ah, bl, acc[j], 0, 0, 0);
      acc[j] = __builtin_amdgcn_mfma_f32_16x16x32_bf16(ah, bh, acc[j], 0, 0, 0);
    }
  }

  // ---- epilogue
  const int b = m0 >> 10;
  const int bh8 = b * 8;
  #pragma unroll
  for (int e = 0; e < 4; e++) {
    const int row = m0 + q * 4 + e;
    const int i = row & 1023;
    #pragma unroll
    for (int j = 0; j < 6; j++) {
      const int nf = hf * 6 + j;
      qkv[(size_t)row * 192 + nf * 16 + r] = acc[j][e];
    }
    if (br == 1 && i % 3 == 0) {
      const int kk = i / 3;
      #pragma unroll
      for (int j = 0; j < 6; j++) {
        const int nf = hf * 6 + j;
        if (nf >= 4) {
          const int col = nf * 16 + r;        // 64..191
          float v = acc[j][e];
          short h, l; bsplit(v, h, l);
          if (col < 128) {                    // K rows
            const int ck = col - 64;
            const int hh = ck >> 3, d = ck & 7;
            KH[(size_t)(bh8 + hh) * 2816 + kk * 8 + d] = h;
            KL[(size_t)(bh8 + hh) * 2816 + kk * 8 + d] = l;
          } else {                            // V^T rows
            const int cv = col - 128;
            const int hh = cv >> 3, d = cv & 7;
            VTh[((size_t)(bh8 + hh) * 16 + d) * 352 + kk] = h;
            VTl[((size_t)(bh8 + hh) * 16 + d) * 352 + kk] = l;
          }
        }
      }
    }
  }
}

// ================= phase 3: one attention unit =================
__device__ __forceinline__ void attn_unit(
    int u, int tid,
    short Pbuf[4][2][2][16][32],
    const float* qkv_g, const float* qkv_l,
    const short* KH, const short* KL,
    const short* VTh, const short* VTl,
    float* o_g, float* pl, float* o_l)
{
  if (u < 2048) {
    const int qt = u & 15, h = (u >> 4) & 7, b = u >> 7;
    const int w = tid >> 6, lane = tid & 63;
    const int quad = lane >> 4, r = lane & 15;
    const int bh = b * 8 + h;
    const int m0 = qt * 64 + w * 16;

    const short8 z8 = {0,0,0,0,0,0,0,0};
    short8 qh = z8, ql = z8;
    if (quad == 0) {
      const float* qp = qkv_g + (size_t)(b * 1024 + m0 + r) * 192 + h * 8;
      float4 a0 = ld4(qp), a1 = ld4(qp + 4);
      float qv[8] = {a0.x, a0.y, a0.z, a0.w, a1.x, a1.y, a1.z, a1.w};
      #pragma unroll
      for (int d = 0; d < 8; d++) { short hh, ll; bsplit(qv[d], hh, ll); qh[d]=hh; ql[d]=ll; }
    }
    const short* kbase  = KH + (size_t)bh * 2816;
    const short* klbase = KL + (size_t)bh * 2816;
    const short* vhbase = VTh + ((size_t)bh * 16 + r) * 352;
    const short* vlbase = VTl + ((size_t)bh * 16 + r) * 352;

    float4v oacc = {0.f, 0.f, 0.f, 0.f};
    short8 vprev_h = z8, vprev_l = z8;

    for (int kc = 0; kc < 11; kc++) {
      short8 vh = *(const short8*)(vhbase + kc * 32 + quad * 8);
      short8 vl = *(const short8*)(vlbase + kc * 32 + quad * 8);

      short8 pA = z8, pB = z8;
      if (kc > 0) {
        pA = *(const short8*)&Pbuf[w][(kc - 1) & 1][0][r][quad * 8];
        pB = *(const short8*)&Pbuf[w][(kc - 1) & 1][1][r][quad * 8];
      }

      short8 kh0 = z8, kl0 = z8, kh1 = z8, kl1 = z8;
      if (quad == 0) {
        kh0 = *(const short8*)(kbase  + (size_t)(kc * 32 + r) * 8);
        kl0 = *(const short8*)(klbase + (size_t)(kc * 32 + r) * 8);
        kh1 = *(const short8*)(kbase  + (size_t)(kc * 32 + 16 + r) * 8);
        kl1 = *(const short8*)(klbase + (size_t)(kc * 32 + 16 + r) * 8);
      }
      float4v s0 = {0.f,0.f,0.f,0.f}, s1 = {0.f,0.f,0.f,0.f};
      s0 = __builtin_amdgcn_mfma_f32_16x16x32_bf16(qh, kl0, s0, 0, 0, 0);
      s0 = __builtin_amdgcn_mfma_f32_16x16x32_bf16(ql, kh0, s0, 0, 0, 0);
      s0 = __builtin_amdgcn_mfma_f32_16x16x32_bf16(qh, kh0, s0, 0, 0, 0);
      s1 = __builtin_amdgcn_mfma_f32_16x16x32_bf16(qh, kl1, s1, 0, 0, 0);
      s1 = __builtin_amdgcn_mfma_f32_16x16x32_bf16(ql, kh1, s1, 0, 0, 0);
      s1 = __builtin_amdgcn_mfma_f32_16x16x32_bf16(qh, kh1, s1, 0, 0, 0);

      if (kc > 0) {
        oacc = __builtin_amdgcn_mfma_f32_16x16x32_bf16(pA, vprev_l, oacc, 0, 0, 0);
        oacc = __builtin_amdgcn_mfma_f32_16x16x32_bf16(pB, vprev_h, oacc, 0, 0, 0);
        oacc = __builtin_amdgcn_mfma_f32_16x16x32_bf16(pA, vprev_h, oacc, 0, 0, 0);
      }

      const int par = kc & 1;
      const int key0 = kc * 32 + r, key1 = key0 + 16;
      #pragma unroll
      for (int e = 0; e < 4; e++) {
        float p0 = (key0 < 342) ? __expf(s0[e] * INV_SQRT8) : 0.f;
        float p1 = (key1 < 342) ? __expf(s1[e] * INV_SQRT8) : 0.f;
        short h0, l0, h1, l1; bsplit(p0, h0, l0); bsplit(p1, h1, l1);
        const int qloc = quad * 4 + e;
        Pbuf[w][par][0][qloc][r]      = h0;
        Pbuf[w][par][0][qloc][16 + r] = h1;
        Pbuf[w][par][1][qloc][r]      = l0;
        Pbuf[w][par][1][qloc][16 + r] = l1;
      }
      vprev_h = vh; vprev_l = vl;
    }
    {
      short8 pA = *(const short8*)&Pbuf[w][0][0][r][quad * 8];
      short8 pB = *(const short8*)&Pbuf[w][0][1][r][quad * 8];
      oacc = __builtin_amdgcn_mfma_f32_16x16x32_bf16(pA, vprev_l, oacc, 0, 0, 0);
      oacc = __builtin_amdgcn_mfma_f32_16x16x32_bf16(pB, vprev_h, oacc, 0, 0, 0);
      oacc = __builtin_amdgcn_mfma_f32_16x16x32_bf16(pA, vprev_h, oacc, 0, 0, 0);
    }

    const int quad2 = (tid & 63) >> 4, r2 = tid & 15;
    #pragma unroll
    for (int e = 0; e < 4; e++) {
      const int orow = b * 1024 + m0 + quad2 * 4 + e;
      if (r2 < 8)       o_g[(size_t)orow * 64 + h * 8 + r2] = oacc[e];
      else if (r2 == 8) pl[(size_t)orow * 8 + h] = oacc[e];
    }
  } else {
    int t = (u - 2048) * 256 + tid;   // 131072
    int h = t & 7;
    int i = (t >> 3) & 1023;
    int b = t >> 13;
    const float* base = qkv_l + (size_t)b * 1024 * 192;
    const float* qp = base + (size_t)i * 192 + h * 8;
    float4 q0 = ld4(qp), q1 = ld4(qp + 4);
    float l = 0.f;
    float4 o0 = make_float4(0.f, 0.f, 0.f, 0.f);
    float4 o1 = make_float4(0.f, 0.f, 0.f, 0.f);
    int jlo = i - 5; if (jlo < 0) jlo = 0;
    int jhi = i + 5; if (jhi > 1023) jhi = 1023;
    for (int j = jlo; j <= jhi; j++) {
      const float* kp = base + (size_t)j * 192 + 64 + h * 8;
      float4 k0 = ld4(kp), k1 = ld4(kp + 4);
      float s = q0.x * k0.x + q0.y * k0.y + q0.z * k0.z + q0.w * k0.w
              + q1.x * k1.x + q1.y * k1.y + q1.z * k1.z + q1.w * k1.w;
      float p = __expf(s * INV_SQRT8);
      l += p;
      float4 v0 = ld4(kp + 64), v1 = ld4(kp + 68);
      o0 = f4fma(p, v0, o0);
      o1 = f4fma(p, v1, o1);
    }
    float inv = 1.f / l;
    float* op = o_l + (size_t)(b * 1024 + i) * 64 + h * 8;
    float4 r0, r1;
    r0.x = o0.x * inv; r0.y = o0.y * inv; r0.z = o0.z * inv; r0.w = o0.w * inv;
    r1.x = o1.x * inv; r1.y = o1.y * inv; r1.z = o1.z * inv; r1.w = o1.w * inv;
    *(float4*)op = r0;
    *(float4*)(op + 4) = r1;
  }
}

// ================= phase 4: fuse GEMM + score for one 32-row unit ========
__device__ __forceinline__ void fuse_unit(
    int bx, int tid,
    float Ls[32][68], float partial[4][64], unsigned* lastflag,
    const float* o_l, const float* o_g, const float* pl, const float* qkv_g,
    const short* Wh, const short* Wl, const float* bc,
    const float* pw1, const float* pb1, const float* pw2, const float* pb2,
    float* num, float* den, unsigned* cnt, float* out)
{
  const int lane = tid & 63, w = tid >> 6;
  const int quad = lane >> 4, r = lane & 15;
  const int t = w >> 1, p = w & 1;        // tile, col-half
  const int m0 = bx * 32 + t * 16;

  float4v acc[2];
  #pragma unroll
  for (int gg = 0; gg < 2; gg++) {
    float bv = bc[(p * 2 + gg) * 16 + r];
    float4v tv = {bv, bv, bv, bv};
    acc[gg] = tv;
  }

  #pragma unroll
  for (int ks = 0; ks < 4; ks++) {
    const int k0 = ks * 32 + quad * 8;
    const int row = m0 + r;
    float av[8];
    if (ks < 2) {
      const float* ap = o_l + (size_t)row * 64 + k0;
      float4 f0 = ld4(ap), f1 = ld4(ap + 4);
      av[0]=f0.x; av[1]=f0.y; av[2]=f0.z; av[3]=f0.w;
      av[4]=f1.x; av[5]=f1.y; av[6]=f1.z; av[7]=f1.w;
    } else {
      const int off = k0 - 64;
      const int h = off >> 3;
      const float* op = o_g + (size_t)row * 64 + off;
      float4 O0 = ld4(op), O1 = ld4(op + 4);
      float l = pl[(size_t)row * 8 + h];
      const int i = row & 1023;
      if (i % 3 != 0) {
        const float* base = qkv_g + (size_t)row * 192;
        const float* qp = base + h * 8;
        const float* kpp = base + 64 + h * 8;
        const float* vp = base + 128 + h * 8;
        float4 q0 = ld4(qp), q1 = ld4(qp + 4);
        float4 k0v = ld4(kpp), k1v = ld4(kpp + 4);
        float s = q0.x*k0v.x + q0.y*k0v.y + q0.z*k0v.z + q0.w*k0v.w
                + q1.x*k1v.x + q1.y*k1v.y + q1.z*k1v.z + q1.w*k1v.w;
        float pd = __expf(s * INV_SQRT8);
        float4 v0 = ld4(vp), v1 = ld4(vp + 4);
        O0 = f4fma(pd, v0, O0); O1 = f4fma(pd, v1, O1);
        l += pd;
      }
      float inv = 1.f / l;
      av[0]=O0.x*inv; av[1]=O0.y*inv; av[2]=O0.z*inv; av[3]=O0.w*inv;
      av[4]=O1.x*inv; av[5]=O1.y*inv; av[6]=O1.z*inv; av[7]=O1.w*inv;
    }
    short8 ah, al;
    #pragma unroll
    for (int i2 = 0; i2 < 8; i2++) { short h2, l2; bsplit(av[i2], h2, l2); ah[i2]=h2; al[i2]=l2; }
    #pragma unroll
    for (int gg = 0; gg < 2; gg++) {
      const int g = p * 2 + gg;
      short8 bh = *(const short8*)(Wh + (size_t)(g * 16 + r) * 128 + k0);
      short8 bl = *(const short8*)(Wl + (size_t)(g * 16 + r) * 128 + k0);
      acc[gg] = __builtin_amdgcn_mfma_f32_16x16x32_bf16(al, bh, acc[gg], 0, 0, 0);
      acc[gg] = __builtin_amdgcn_mfma_f32_16x16x32_bf16(ah, bl, acc[gg], 0, 0, 0);
      acc[gg] = __builtin_amdgcn_mfma_f32_16x16x32_bf16(ah, bh, acc[gg], 0, 0, 0);
    }
  }

  #pragma unroll
  for (int gg = 0; gg < 2; gg++)
    #pragma unroll
    for (int e = 0; e < 4; e++)
      Ls[t * 16 + quad * 4 + e][(p * 2 + gg) * 16 + r] = acc[gg][e];
  __syncthreads();

  const int row31 = lane & 31, half = lane >> 5;
  float4 fr[16];
  #pragma unroll
  for (int e = 0; e < 16; e++) fr[e] = *(float4*)&Ls[row31][e * 4];

  float psc = 0.f;
  #pragma unroll
  for (int jj = 0; jj < 4; jj++) {
    const int j = w * 8 + half * 4 + jj;
    const float* wr = pw1 + j * 64;
    float hj = pb1[j];
    #pragma unroll
    for (int e = 0; e < 16; e++) {
      float4 wv = ld4(wr + e * 4);
      hj += fr[e].x * wv.x + fr[e].y * wv.y + fr[e].z * wv.z + fr[e].w * wv.w;
    }
    float e2 = __expf(2.f * hj);
    psc += ((e2 - 1.f) / (e2 + 1.f)) * pw2[j];   // tanh via exp
  }
  partial[w][lane] = psc;
  __syncthreads();
  if (w == 0) {
    const int b = bx >> 5;
    float pv = 0.f;
    if (lane < 32) {
      float sc = pb2[0];
      #pragma unroll
      for (int w2 = 0; w2 < 4; w2++)
        sc += partial[w2][lane] + partial[w2][lane + 32];
      pv = __expf(sc);
      #pragma unroll
      for (int e = 0; e < 16; e++) {
        Ls[lane][e*4+0] = pv * fr[e].x; Ls[lane][e*4+1] = pv * fr[e].y;
        Ls[lane][e*4+2] = pv * fr[e].z; Ls[lane][e*4+3] = pv * fr[e].w;
      }
    }
    float colsum = 0.f;
    #pragma unroll 8
    for (int s = 0; s < 32; s++) colsum += Ls[s][lane];
    atomicAdd(&num[b * 64 + lane], colsum);
    float ps = pv;
    #pragma unroll
    for (int off = 32; off > 0; off >>= 1)
      ps += __shfl_xor(ps, off, 64);
    if (lane == 0) atomicAdd(&den[b], ps);
  }

  // last-block finalize
  if (tid == 0) {
    __threadfence();
    *lastflag = (atomicAdd(cnt, 1u) == 511u) ? 1u : 0u;
  }
  __syncthreads();
  if (*lastflag) {
    __threadfence();
    for (int k = tid; k < 1024; k += 256) {
      float nv = __hip_atomic_load(&num[k], __ATOMIC_RELAXED, __HIP_MEMORY_SCOPE_AGENT);
      float dv = __hip_atomic_load(&den[k >> 6], __ATOMIC_RELAXED, __HIP_MEMORY_SCOPE_AGENT);
      out[k] = nv / dv;
    }
  }
}

// ================= fused cooperative kernel =================
__global__ __launch_bounds__(256, 4) void fused_all(
    const float* __restrict__ X,  const float* __restrict__ PW,
    const float* __restrict__ PB,
    const float* __restrict__ LIW, const float* __restrict__ LIB,
    const float* __restrict__ GIW, const float* __restrict__ GIB,
    const float* __restrict__ LOW, const float* __restrict__ GOW,
    const float* __restrict__ LOB, const float* __restrict__ GOB,
    const float* __restrict__ FW,  const float* __restrict__ FB,
    const float* __restrict__ PW1, const float* __restrict__ PB1,
    const float* __restrict__ PW2, const float* __restrict__ PB2,
    short* __restrict__ wb, float* __restrict__ bc, float* __restrict__ numden,
    float* __restrict__ qkv_l, float* __restrict__ qkv_g,
    float* __restrict__ o_l, float* __restrict__ o_g, float* __restrict__ pl,
    short* __restrict__ KH, short* __restrict__ KL,
    short* __restrict__ VTh, short* __restrict__ VTl,
    float* __restrict__ out)
{
  __shared__ __align__(16) short XPH[16][72];
  __shared__ __align__(16) short XPL[16][72];
  __shared__ short Pbuf[4][2][2][16][32];
  __shared__ float Ls[32][68];
  __shared__ float partial[4][64];
  __shared__ unsigned lastflag;

  cg::grid_group grid = cg::this_grid();
  const int tid = threadIdx.x;
  const int bid = blockIdx.x;

  const short* projh = wb;         const short* projl = wb + 20480;
  const short* linh = wb + 40960;  const short* linl = wb + 53248;
  const short* ginh = wb + 65536;  const short* ginl = wb + 77824;
  const short* wfh = wb + 90112;   const short* wfl = wb + 98304;
  float* num = numden; float* den = numden + 1024;
  unsigned* cnt = (unsigned*)(numden + 1040);

  // phase 1: prep (423936 items, stride 262144)
  for (unsigned idx = (unsigned)bid * 256u + tid; idx < 423936u; idx += 262144u)
    prep_item(idx, PW, LIW, GIW, FW, LOW, GOW, LOB, GOB, FB,
              wb, bc, numden, VTh, VTl);
  grid.sync();

  // phase 2: proj + qkv (1024 tiles)
  proj_qkv_tile(bid * 16, tid, XPH, XPL, X, projh, projl, PB,
                linh, linl, ginh, ginl, LIB, GIB,
                qkv_l, qkv_g, KH, KL, VTh, VTl);
  grid.sync();

  // phase 3: attention (2560 units)
  for (int u = bid; u < 2560; u += 1024)
    attn_unit(u, tid, Pbuf, qkv_g, qkv_l, KH, KL, VTh, VTl, o_g, pl, o_l);
  grid.sync();

  // phase 4: fuse + score (512 units) + cnt finalize
  if (bid < 512)
    fuse_unit(bid, tid, Ls, partial, &lastflag,
              o_l, o_g, pl, qkv_g, wfh, wfl, bc,
              PW1, PB1, PW2, PB2, num, den, cnt, out);
}

// ================= fallback kernels (R16 4-dispatch pipeline) ============
__global__ __launch_bounds__(256) void prep_w_k(
    const float* __restrict__ PW, const float* __restrict__ LIW,
    const float* __restrict__ GIW, const float* __restrict__ FW,
    const float* __restrict__ LOW, const float* __restrict__ GOW,
    const float* __restrict__ LOB, const float* __restrict__ GOB,
    const float* __restrict__ FB,
    short* __restrict__ wb, float* __restrict__ bc, float* __restrict__ numden,
    short* __restrict__ VTh, short* __restrict__ VTl)
{
  unsigned idx = blockIdx.x * 256 + threadIdx.x;
  prep_item(idx, PW, LIW, GIW, FW, LOW, GOW, LOB, GOB, FB,
            wb, bc, numden, VTh, VTl);
}

__global__ __launch_bounds__(256) void gemm_proj_qkv_k(
    const float* __restrict__ X,
    const short* __restrict__ PWh, const short* __restrict__ PWl,
    const float* __restrict__ pb,
    const short* __restrict__ LWh, const short* __restrict__ LWl,
    const short* __restrict__ GWh, const short* __restrict__ GWl,
    const float* __restrict__ lb, const float* __restrict__ gb,
    float* __restrict__ qkv_l, float* __restrict__ qkv_g,
    short* __restrict__ KH, short* __restrict__ KL,
    short* __restrict__ VTh, short* __restrict__ VTl)
{
  __shared__ __align__(16) short XPH[16][72];
  __shared__ __align__(16) short XPL[16][72];
  proj_qkv_tile(blockIdx.x * 16, threadIdx.x, XPH, XPL, X, PWh, PWl, pb,
                LWh, LWl, GWh, GWl, lb, gb, qkv_l, qkv_g, KH, KL, VTh, VTl);
}

__global__ __launch_bounds__(256) void attn_k(
    const float* __restrict__ qkv_g, const float* __restrict__ qkv_l,
    const short* __restrict__ KH, const short* __restrict__ KL,
    const short* __restrict__ VTh, const short* __restrict__ VTl,
    float* __restrict__ o_g, float* __restrict__ pl, float* __restrict__ o_l)
{
  __shared__ short Pbuf[4][2][2][16][32];
  attn_unit(blockIdx.x, threadIdx.x, Pbuf, qkv_g, qkv_l, KH, KL, VTh, VTl,
            o_g, pl, o_l);
}

__global__ __launch_bounds__(256) void gemm_fuse_score_k(
    const float* __restrict__ o_l, const float* __restrict__ o_g,
    const float* __restrict__ pl, const float* __restrict__ qkv_g,
    const short* __restrict__ Wh, const short* __restrict__ Wl,
    const float* __restrict__ bc,
    const float* __restrict__ pw1, const float* __restrict__ pb1,
    const float* __restrict__ pw2, const float* __restrict__ pb2,
    float* __restrict__ num, float* __restrict__ den,
    unsigned* __restrict__ cnt, float* __restrict__ out)
{
  __shared__ float Ls[32][68];
  __shared__ float partial[4][64];
  __shared__ unsigned lastflag;
  fuse_unit(blockIdx.x, threadIdx.x, Ls, partial, &lastflag,
            o_l, o_g, pl, qkv_g, Wh, Wl, bc, pw1, pb1, pw2, pb2,
            num, den, cnt, out);
}

extern "C" void kernel_launch(void* const* d_in, const int* in_sizes, int n_in,
                              void* d_out, int out_size, void* d_ws, size_t ws_size,
                              hipStream_t stream)
{
  const float* x          = (const float*)d_in[0];
  const float* proj_w     = (const float*)d_in[1];
  const float* proj_b     = (const float*)d_in[2];
  const float* loc_in_w   = (const float*)d_in[3];
  const float* loc_in_b   = (const float*)d_in[4];
  const float* loc_out_w  = (const float*)d_in[5];
  const float* loc_out_b  = (const float*)d_in[6];
  const float* glob_in_w  = (const float*)d_in[7];
  const float* glob_in_b  = (const float*)d_in[8];
  const float* glob_out_w = (const float*)d_in[9];
  const float* glob_out_b = (const float*)d_in[10];
  const float* fusion_w   = (const float*)d_in[11];
  const float* fusion_b   = (const float*)d_in[12];
  const float* pw1        = (const float*)d_in[13];
  const float* pb1        = (const float*)d_in[14];
  const float* pw2        = (const float*)d_in[15];
  const float* pb2        = (const float*)d_in[16];

  float* ws = (float*)d_ws;
  float* qkv_g = ws;
  float* qkv_l = ws + 4587520;
  float* o_l   = ws + 7733248;
  float* o_g   = ws + 8781824;
  float* pl    = ws + 9830400;
  short* KH    = (short*)(ws + 9961472);
  short* KL    = (short*)(ws + 10141696);
  short* VTh   = (short*)(ws + 10321920);
  short* VTl   = (short*)(ws + 10682368);
  float* bc    = ws + 11042816;
  float* numden= ws + 11042880;
  float* num   = numden;
  float* den   = numden + 1024;
  unsigned* cnt= (unsigned*)(numden + 1040);
  short* wb    = (short*)(ws + 11043921);
  short* projh = wb;           short* projl = wb + 20480;
  short* linh  = wb + 40960;   short* linl  = wb + 53248;
  short* ginh  = wb + 65536;   short* ginl  = wb + 77824;
  short* wfh   = wb + 90112;   short* wfl   = wb + 98304;
  float* out   = (float*)d_out;

  // Try the single cooperative launch; fall back to 4 dispatches on error.
  void* args[] = {
    (void*)&x, (void*)&proj_w, (void*)&proj_b,
    (void*)&loc_in_w, (void*)&loc_in_b, (void*)&glob_in_w, (void*)&glob_in_b,
    (void*)&loc_out_w, (void*)&glob_out_w, (void*)&loc_out_b, (void*)&glob_out_b,
    (void*)&fusion_w, (void*)&fusion_b,
    (void*)&pw1, (void*)&pb1, (void*)&pw2, (void*)&pb2,
    (void*)&wb, (void*)&bc, (void*)&numden,
    (void*)&qkv_l, (void*)&qkv_g, (void*)&o_l, (void*)&o_g, (void*)&pl,
    (void*)&KH, (void*)&KL, (void*)&VTh, (void*)&VTl,
    (void*)&out
  };
  hipError_t err = hipLaunchCooperativeKernel(
      (const void*)fused_all, dim3(1024), dim3(256), args, 0, stream);

  if (err != hipSuccess) {
    dim3 blk(256);
    prep_w_k<<<1656, blk, 0, stream>>>(proj_w, loc_in_w, glob_in_w, fusion_w,
                                       loc_out_w, glob_out_w, loc_out_b,
                                       glob_out_b, fusion_b, wb, bc, numden,
                                       VTh, VTl);
    gemm_proj_qkv_k<<<1024, blk, 0, stream>>>(
        x, projh, projl, proj_b, linh, linl, ginh, ginl, loc_in_b, glob_in_b,
        qkv_l, qkv_g, KH, KL, VTh, VTl);
    attn_k<<<2560, blk, 0, stream>>>(qkv_g, qkv_l, KH, KL, VTh, VTl,
                                     o_g, pl, o_l);
    gemm_fuse_score_k<<<512, blk, 0, stream>>>(
        o_l, o_g, pl, qkv_g, wfh, wfl, bc, pw1, pb1, pw2, pb2,
        num, den, cnt, out);
  }
}

// Round 8
// 180.743 us; speedup vs baseline: 3.3694x; 3.3694x over previous
//
#include <hip/hip_runtime.h>
#include <hip/hip_bf16.h>

// Shapes: B=16, S=1024, E=64, H=8, d=8, INPUT_DIM=310
// local mask: |i-j|<=5 (11 keys); sparse mask: j%3==0 or i==j (342 keys + diag)
//
// R18 = R14 (best fill-normalized config) + Pbuf bank-conflict fix in attn:
// rows padded 32->36 shorts (72 B): the P-store's four quad-rows now start at
// banks {0,8,16,24} instead of all at 0 (was an 8-way write conflict every
// store). Transpose read becomes 2x ds_read_b64 (72 B rows keep only 8 B
// alignment for odd rows).
// Structure (4 dispatches):
//  1. prep_w        — weight split + fused fusion W + bc + numden/cnt + VT pads
//  2. gemm_proj_qkv — proj GEMM -> xp in LDS (bf16 hi/lo) -> qkv GEMM both
//                     branches; epilogue writes qkv fp32 AND K/V bf16 buffers
//  3. attn          — global MFMA attention (2048) + local attention (512)
//  4. gemm_fuse_score (+ last-block finalize: out = num/den)
// GEMMs + global attention via mfma_f32_16x16x32_bf16, fp32 = hi+lo bf16 split.
// A-frag A[m=lane&15][k=quad*8+j]; B-frag B[n=lane&15][k=quad*8+j];
// C/D: col=lane&15, row=quad*4+reg.

typedef __attribute__((ext_vector_type(8))) short short8;
typedef __attribute__((ext_vector_type(4))) short short4v;
typedef __attribute__((ext_vector_type(4))) float float4v;

#define INV_SQRT8 0.3535533905932738f

__device__ __forceinline__ float4 ld4(const float* p) { return *(const float4*)p; }

__device__ __forceinline__ float4 f4fma(float s, float4 w, float4 a) {
  a.x = fmaf(s, w.x, a.x); a.y = fmaf(s, w.y, a.y);
  a.z = fmaf(s, w.z, a.z); a.w = fmaf(s, w.w, a.w);
  return a;
}

// fp32 -> bf16 via native converter (compiler emits v_cvt_pk_bf16_f32 path).
__device__ __forceinline__ short f2bf(float x) {
  __hip_bfloat16 b = __float2bfloat16(x);
  unsigned short u; __builtin_memcpy(&u, &b, 2);
  return (short)u;
}
__device__ __forceinline__ float bf2f(short s) {
  return __uint_as_float(((unsigned)(unsigned short)s) << 16);
}
// fp32 -> (bf16 hi, bf16 lo); lo = x - hi exact in fp32.
__device__ __forceinline__ void bsplit(float x, short& h, short& l) {
  h = f2bf(x);
  l = f2bf(x - bf2f(h));
}

// ---------------- prep_w: split weights + fused fusion weights + bc + zero
// num/den/cnt + VT constant pads (ones row n=8, zero rows n>8, kk>=342 pads).
__global__ __launch_bounds__(256) void prep_w(
    const float* __restrict__ pw, const float* __restrict__ liw,
    const float* __restrict__ giw, const float* __restrict__ fw,
    const float* __restrict__ low, const float* __restrict__ gow,
    const float* __restrict__ lob, const float* __restrict__ gob,
    const float* __restrict__ fb,
    short* __restrict__ wb, float* __restrict__ bc, float* __restrict__ numden,
    short* __restrict__ VTh, short* __restrict__ VTl)
{
  unsigned idx = blockIdx.x * 256 + threadIdx.x;
  if (idx < 53248u) {
    float v; unsigned ho, lo_;
    if (idx < 20480u) {           // proj, padded K 310->320
      unsigned r = idx / 320u, k = idx - r * 320u;
      v = (k < 310u) ? pw[r * 310u + k] : 0.f;
      ho = 0u + idx; lo_ = 20480u + idx;
    } else if (idx < 32768u) {    // loc_in
      unsigned i = idx - 20480u; v = liw[i]; ho = 40960u + i; lo_ = 53248u + i;
    } else if (idx < 45056u) {    // glob_in
      unsigned i = idx - 32768u; v = giw[i]; ho = 65536u + i; lo_ = 77824u + i;
    } else {                      // fused fusion weight W12[n][k]
      unsigned i = idx - 45056u;
      unsigned n = i >> 7, k = i & 127u;
      float s = 0.f;
      if (k < 64u) {
        for (int e = 0; e < 64; e++) s += fw[n * 128 + e] * low[e * 64 + k];
      } else {
        for (int e = 0; e < 64; e++) s += fw[n * 128 + 64 + e] * gow[e * 64 + (k - 64u)];
      }
      v = s; ho = 90112u + i; lo_ = 98304u + i;
    }
    short h, l; bsplit(v, h, l);
    wb[ho] = h; wb[lo_] = l;
    if (idx < 64u) {
      float b = fb[idx];
      for (int e = 0; e < 64; e++)
        b += lob[e] * fw[idx * 128 + e] + gob[e] * fw[idx * 128 + 64 + e];
      bc[idx] = b;
    }
    if (idx < 1041u) numden[idx] = 0.f;   // num[1024] + den[16] + cnt
  } else {
    // VT constant pads. Data rows (n<8, kk<342) come from gemm_proj_qkv.
    unsigned t = idx - 53248u;
    if (t < 370688u) {
      unsigned pos; short hv = 0;
      if (t < 360448u) {                // n in [8,16): ones row / zeros, 128 bh
        unsigned bh = t / 2816u;        // 8*352
        unsigned rem = t - bh * 2816u;
        unsigned n8 = rem / 352u;
        unsigned kk = rem - n8 * 352u;
        pos = (bh * 16u + 8u + n8) * 352u + kk;
        if (n8 == 0u) hv = (short)0x3F80;   // bf16(1.0)
      } else {                          // n<8, kk in [342,352): zero pad
        unsigned t2 = t - 360448u;      // < 10240
        unsigned bh = t2 / 80u;
        unsigned rem = t2 - bh * 80u;
        unsigned n = rem / 10u;
        unsigned kk = 342u + (rem - n * 10u);
        pos = (bh * 16u + n) * 352u + kk;
      }
      VTh[pos] = hv; VTl[pos] = 0;
    }
  }
}

// ---------------- fused proj + qkv GEMM (R14 64-row block version).
__global__ __launch_bounds__(256) void gemm_proj_qkv(
    const float* __restrict__ X,
    const short* __restrict__ PWh, const short* __restrict__ PWl,
    const float* __restrict__ pb,
    const short* __restrict__ LWh, const short* __restrict__ LWl,
    const short* __restrict__ GWh, const short* __restrict__ GWl,
    const float* __restrict__ lb, const float* __restrict__ gb,
    float* __restrict__ qkv_l, float* __restrict__ qkv_g,
    short* __restrict__ KH, short* __restrict__ KL,
    short* __restrict__ VTh, short* __restrict__ VTl)
{
  __shared__ __align__(16) short XPH[64][72];
  __shared__ __align__(16) short XPL[64][72];
  const int lane = threadIdx.x & 63;
  const int w = threadIdx.x >> 6;
  const int q = lane >> 4, r = lane & 15;
  const int mloc = w * 16;
  const int m0 = blockIdx.x * 64 + mloc;

  // ---- phase A: proj
  float4v accp[4];
  #pragma unroll
  for (int g = 0; g < 4; g++) {
    float bv = pb[g * 16 + r];
    float4v t = {bv, bv, bv, bv};
    accp[g] = t;
  }
  const float* arow = X + (size_t)(m0 + r) * 310;
  #pragma unroll
  for (int ks = 0; ks < 10; ks++) {
    const int k0 = ks * 32 + q * 8;
    float av[8];
    if (ks < 9) {
      const float* ap = arow + k0;
      #pragma unroll
      for (int t = 0; t < 4; t++) {
        float2 f = *(const float2*)(ap + t * 2);
        av[t*2] = f.x; av[t*2+1] = f.y;
      }
    } else {
      #pragma unroll
      for (int j = 0; j < 8; j++) {
        int kidx = k0 + j;
        av[j] = (kidx < 310) ? arow[kidx] : 0.f;
      }
    }
    short8 ah, al;
    #pragma unroll
    for (int i = 0; i < 8; i++) { short h, l; bsplit(av[i], h, l); ah[i]=h; al[i]=l; }
    #pragma unroll
    for (int g = 0; g < 4; g++) {
      short8 bh = *(const short8*)(PWh + (size_t)(g * 16 + r) * 320 + k0);
      short8 bl = *(const short8*)(PWl + (size_t)(g * 16 + r) * 320 + k0);
      accp[g] = __builtin_amdgcn_mfma_f32_16x16x32_bf16(al, bh, accp[g], 0, 0, 0);
      accp[g] = __builtin_amdgcn_mfma_f32_16x16x32_bf16(ah, bl, accp[g], 0, 0, 0);
      accp[g] = __builtin_amdgcn_mfma_f32_16x16x32_bf16(ah, bh, accp[g], 0, 0, 0);
    }
  }
  // xp tile -> LDS bf16 hi/lo (wave-local rows => no barrier)
  #pragma unroll
  for (int g = 0; g < 4; g++)
    #pragma unroll
    for (int e = 0; e < 4; e++) {
      short h, l; bsplit(accp[g][e], h, l);
      XPH[mloc + q * 4 + e][g * 16 + r] = h;
      XPL[mloc + q * 4 + e][g * 16 + r] = l;
    }

  // ---- phase B: qkv both branches, K=64
  float4v acc[2][12];
  #pragma unroll
  for (int nf = 0; nf < 12; nf++) {
    float bv0 = lb[nf * 16 + r], bv1 = gb[nf * 16 + r];
    float4v t0 = {bv0, bv0, bv0, bv0};
    float4v t1 = {bv1, bv1, bv1, bv1};
    acc[0][nf] = t0; acc[1][nf] = t1;
  }
  #pragma unroll
  for (int ks = 0; ks < 2; ks++) {
    const int k0 = ks * 32 + q * 8;
    short8 ah = *(const short8*)&XPH[mloc + r][k0];
    short8 al = *(const short8*)&XPL[mloc + r][k0];
    #pragma unroll
    for (int nf = 0; nf < 12; nf++) {
      short8 bh0 = *(const short8*)(LWh + (size_t)(nf * 16 + r) * 64 + k0);
      short8 bl0 = *(const short8*)(LWl + (size_t)(nf * 16 + r) * 64 + k0);
      acc[0][nf] = __builtin_amdgcn_mfma_f32_16x16x32_bf16(al, bh0, acc[0][nf], 0, 0, 0);
      acc[0][nf] = __builtin_amdgcn_mfma_f32_16x16x32_bf16(ah, bl0, acc[0][nf], 0, 0, 0);
      acc[0][nf] = __builtin_amdgcn_mfma_f32_16x16x32_bf16(ah, bh0, acc[0][nf], 0, 0, 0);
      short8 bh1 = *(const short8*)(GWh + (size_t)(nf * 16 + r) * 64 + k0);
      short8 bl1 = *(const short8*)(GWl + (size_t)(nf * 16 + r) * 64 + k0);
      acc[1][nf] = __builtin_amdgcn_mfma_f32_16x16x32_bf16(al, bh1, acc[1][nf], 0, 0, 0);
      acc[1][nf] = __builtin_amdgcn_mfma_f32_16x16x32_bf16(ah, bl1, acc[1][nf], 0, 0, 0);
      acc[1][nf] = __builtin_amdgcn_mfma_f32_16x16x32_bf16(ah, bh1, acc[1][nf], 0, 0, 0);
    }
  }

  // ---- epilogue
  const int b = m0 >> 10;           // 64-row blocks never straddle a batch
  const int bh8 = b * 8;
  #pragma unroll
  for (int e = 0; e < 4; e++) {
    const int row = m0 + q * 4 + e;
    const int i = row & 1023;
    #pragma unroll
    for (int nf = 0; nf < 12; nf++) {
      qkv_l[(size_t)row * 192 + nf * 16 + r] = acc[0][nf][e];
      qkv_g[(size_t)row * 192 + nf * 16 + r] = acc[1][nf][e];
    }
    if (i % 3 == 0) {
      const int kk = i / 3;         // 0..341
      #pragma unroll
      for (int nf = 4; nf < 12; nf++) {
        const int col = nf * 16 + r;        // 64..191
        float v = acc[1][nf][e];
        short h, l; bsplit(v, h, l);
        if (col < 128) {                    // K rows
          const int ck = col - 64;
          const int hh = ck >> 3, d = ck & 7;
          KH[(size_t)(bh8 + hh) * 2816 + kk * 8 + d] = h;
          KL[(size_t)(bh8 + hh) * 2816 + kk * 8 + d] = l;
        } else {                            // V^T rows
          const int cv = col - 128;
          const int hh = cv >> 3, d = cv & 7;
          VTh[((size_t)(bh8 + hh) * 16 + d) * 352 + kk] = h;
          VTl[((size_t)(bh8 + hh) * 16 + d) * 352 + kk] = l;
        }
      }
    }
  }
}

// ---------------- attention: blocks [0,2048) = MFMA global attention,
// blocks [2048,2560) = local sliding-window attention (independent work).
// Pbuf rows padded to 36 shorts (72 B): P-store quad-rows hit banks
// {0,8,16,24}+r/2 (was all-bank-0 => 8-way conflict). Transpose read via
// 2x ds_read_b64 (8 B alignment). KH pads kk>=342 poison — safe (p masked 0).
__global__ __launch_bounds__(256) void attn(
    const float* __restrict__ qkv_g, const float* __restrict__ qkv_l,
    const short* __restrict__ KH, const short* __restrict__ KL,
    const short* __restrict__ VTh, const short* __restrict__ VTl,
    float* __restrict__ o_g, float* __restrict__ pl, float* __restrict__ o_l)
{
  __shared__ short Pbuf[4][2][2][16][36];   // wave, parity, hi/lo, q, k(+pad)
  const int u = blockIdx.x;
  if (u < 2048) {
    const int qt = u & 15, h = (u >> 4) & 7, b = u >> 7;
    const int w = threadIdx.x >> 6, lane = threadIdx.x & 63;
    const int quad = lane >> 4, r = lane & 15;
    const int bh = b * 8 + h;
    const int m0 = qt * 64 + w * 16;

    const short8 z8 = {0,0,0,0,0,0,0,0};
    short8 qh = z8, ql = z8;
    if (quad == 0) {
      const float* qp = qkv_g + (size_t)(b * 1024 + m0 + r) * 192 + h * 8;
      float4 a0 = ld4(qp), a1 = ld4(qp + 4);
      float qv[8] = {a0.x, a0.y, a0.z, a0.w, a1.x, a1.y, a1.z, a1.w};
      #pragma unroll
      for (int d = 0; d < 8; d++) { short hh, ll; bsplit(qv[d], hh, ll); qh[d]=hh; ql[d]=ll; }
    }
    const short* kbase  = KH + (size_t)bh * 2816;
    const short* klbase = KL + (size_t)bh * 2816;
    const short* vhbase = VTh + ((size_t)bh * 16 + r) * 352;
    const short* vlbase = VTl + ((size_t)bh * 16 + r) * 352;

    float4v oacc = {0.f, 0.f, 0.f, 0.f};

    for (int kc = 0; kc < 11; kc++) {
      short8 kh0 = z8, kl0 = z8, kh1 = z8, kl1 = z8;
      if (quad == 0) {
        kh0 = *(const short8*)(kbase  + (size_t)(kc * 32 + r) * 8);
        kl0 = *(const short8*)(klbase + (size_t)(kc * 32 + r) * 8);
        kh1 = *(const short8*)(kbase  + (size_t)(kc * 32 + 16 + r) * 8);
        kl1 = *(const short8*)(klbase + (size_t)(kc * 32 + 16 + r) * 8);
      }
      float4v s0 = {0.f,0.f,0.f,0.f}, s1 = {0.f,0.f,0.f,0.f};
      s0 = __builtin_amdgcn_mfma_f32_16x16x32_bf16(qh, kl0, s0, 0, 0, 0);
      s0 = __builtin_amdgcn_mfma_f32_16x16x32_bf16(ql, kh0, s0, 0, 0, 0);
      s0 = __builtin_amdgcn_mfma_f32_16x16x32_bf16(qh, kh0, s0, 0, 0, 0);
      s1 = __builtin_amdgcn_mfma_f32_16x16x32_bf16(qh, kl1, s1, 0, 0, 0);
      s1 = __builtin_amdgcn_mfma_f32_16x16x32_bf16(ql, kh1, s1, 0, 0, 0);
      s1 = __builtin_amdgcn_mfma_f32_16x16x32_bf16(qh, kh1, s1, 0, 0, 0);

      const int par = kc & 1;
      const int key0 = kc * 32 + r, key1 = key0 + 16;
      #pragma unroll
      for (int e = 0; e < 4; e++) {
        float p0 = (key0 < 342) ? __expf(s0[e] * INV_SQRT8) : 0.f;
        float p1 = (key1 < 342) ? __expf(s1[e] * INV_SQRT8) : 0.f;
        short h0, l0, h1, l1; bsplit(p0, h0, l0); bsplit(p1, h1, l1);
        const int qloc = quad * 4 + e;
        Pbuf[w][par][0][qloc][r]      = h0;
        Pbuf[w][par][0][qloc][16 + r] = h1;
        Pbuf[w][par][1][qloc][r]      = l0;
        Pbuf[w][par][1][qloc][16 + r] = l1;
      }
      // Same-wave LDS transpose read (DS ops in-order per wave; no barrier).
      short4v a0 = *(const short4v*)&Pbuf[w][par][0][r][quad * 8];
      short4v a1 = *(const short4v*)&Pbuf[w][par][0][r][quad * 8 + 4];
      short4v b0 = *(const short4v*)&Pbuf[w][par][1][r][quad * 8];
      short4v b1 = *(const short4v*)&Pbuf[w][par][1][r][quad * 8 + 4];
      short8 pA = {a0[0],a0[1],a0[2],a0[3],a1[0],a1[1],a1[2],a1[3]};
      short8 pB = {b0[0],b0[1],b0[2],b0[3],b1[0],b1[1],b1[2],b1[3]};
      short8 vh = *(const short8*)(vhbase + kc * 32 + quad * 8);
      short8 vl = *(const short8*)(vlbase + kc * 32 + quad * 8);
      oacc = __builtin_amdgcn_mfma_f32_16x16x32_bf16(pA, vl, oacc, 0, 0, 0);
      oacc = __builtin_amdgcn_mfma_f32_16x16x32_bf16(pB, vh, oacc, 0, 0, 0);
      oacc = __builtin_amdgcn_mfma_f32_16x16x32_bf16(pA, vh, oacc, 0, 0, 0);
    }

    #pragma unroll
    for (int e = 0; e < 4; e++) {
      const int orow = b * 1024 + m0 + quad * 4 + e;
      if (r < 8)       o_g[(size_t)orow * 64 + h * 8 + r] = oacc[e];
      else if (r == 8) pl[(size_t)orow * 8 + h] = oacc[e];
    }
  } else {
    int t = (u - 2048) * 256 + threadIdx.x;   // 131072
    int h = t & 7;
    int i = (t >> 3) & 1023;
    int b = t >> 13;
    const float* base = qkv_l + (size_t)b * 1024 * 192;
    const float* qp = base + (size_t)i * 192 + h * 8;
    float4 q0 = ld4(qp), q1 = ld4(qp + 4);
    float l = 0.f;
    float4 o0 = make_float4(0.f, 0.f, 0.f, 0.f);
    float4 o1 = make_float4(0.f, 0.f, 0.f, 0.f);
    int jlo = i - 5; if (jlo < 0) jlo = 0;
    int jhi = i + 5; if (jhi > 1023) jhi = 1023;
    for (int j = jlo; j <= jhi; j++) {
      const float* kp = base + (size_t)j * 192 + 64 + h * 8;
      float4 k0 = ld4(kp), k1 = ld4(kp + 4);
      float s = q0.x * k0.x + q0.y * k0.y + q0.z * k0.z + q0.w * k0.w
              + q1.x * k1.x + q1.y * k1.y + q1.z * k1.z + q1.w * k1.w;
      float p = __expf(s * INV_SQRT8);
      l += p;
      float4 v0 = ld4(kp + 64), v1 = ld4(kp + 68);
      o0 = f4fma(p, v0, o0);
      o1 = f4fma(p, v1, o1);
    }
    float inv = 1.f / l;
    float* op = o_l + (size_t)(b * 1024 + i) * 64 + h * 8;
    float4 r0, r1;
    r0.x = o0.x * inv; r0.y = o0.y * inv; r0.z = o0.z * inv; r0.w = o0.w * inv;
    r1.x = o1.x * inv; r1.y = o1.y * inv; r1.z = o1.z * inv; r1.w = o1.w * inv;
    *(float4*)op = r0;
    *(float4*)(op + 4) = r1;
  }
}

// ---------------- Fusion GEMM + score + pool partials, fused via LDS.
// Block = 64 rows (grid 256). Wave w: rows w*16..+16, ALL 64 cols (4 frags).
// Diag-key + 1/l normalization folded into A-load. Last block finalizes.
__global__ __launch_bounds__(256) void gemm_fuse_score(
    const float* __restrict__ o_l, const float* __restrict__ o_g,
    const float* __restrict__ pl, const float* __restrict__ qkv_g,
    const short* __restrict__ Wh, const short* __restrict__ Wl,
    const float* __restrict__ bc,
    const float* __restrict__ pw1, const float* __restrict__ pb1,
    const float* __restrict__ pw2, const float* __restrict__ pb2,
    float* __restrict__ num, float* __restrict__ den,
    unsigned* __restrict__ cnt, float* __restrict__ out)
{
  __shared__ float Ls[64][68];
  __shared__ float partial[4][64];
  __shared__ unsigned lastflag;
  const int tid = threadIdx.x;
  const int lane = tid & 63, w = tid >> 6;
  const int quad = lane >> 4, r = lane & 15;
  const int bx = blockIdx.x;
  const int m0 = bx * 64 + w * 16;

  float4v acc[4];
  #pragma unroll
  for (int g = 0; g < 4; g++) {
    float bv = bc[g * 16 + r];
    float4v t = {bv, bv, bv, bv};
    acc[g] = t;
  }

  #pragma unroll
  for (int ks = 0; ks < 4; ks++) {
    const int k0 = ks * 32 + quad * 8;
    const int row = m0 + r;
    float av[8];
    if (ks < 2) {   // local branch, already normalized
      const float* ap = o_l + (size_t)row * 64 + k0;
      float4 f0 = ld4(ap), f1 = ld4(ap + 4);
      av[0]=f0.x; av[1]=f0.y; av[2]=f0.z; av[3]=f0.w;
      av[4]=f1.x; av[5]=f1.y; av[6]=f1.z; av[7]=f1.w;
    } else {        // global branch: unnormalized O + diag + normalize
      const int off = k0 - 64;
      const int h = off >> 3;
      const float* op = o_g + (size_t)row * 64 + off;
      float4 O0 = ld4(op), O1 = ld4(op + 4);
      float l = pl[(size_t)row * 8 + h];
      const int i = row & 1023;
      if (i % 3 != 0) {
        const float* base = qkv_g + (size_t)row * 192;
        const float* qp = base + h * 8;
        const float* kpp = base + 64 + h * 8;
        const float* vp = base + 128 + h * 8;
        float4 q0 = ld4(qp), q1 = ld4(qp + 4);
        float4 k0v = ld4(kpp), k1v = ld4(kpp + 4);
        float s = q0.x*k0v.x + q0.y*k0v.y + q0.z*k0v.z + q0.w*k0v.w
                + q1.x*k1v.x + q1.y*k1v.y + q1.z*k1v.z + q1.w*k1v.w;
        float p = __expf(s * INV_SQRT8);
        float4 v0 = ld4(vp), v1 = ld4(vp + 4);
        O0 = f4fma(p, v0, O0); O1 = f4fma(p, v1, O1);
        l += p;
      }
      float inv = 1.f / l;
      av[0]=O0.x*inv; av[1]=O0.y*inv; av[2]=O0.z*inv; av[3]=O0.w*inv;
      av[4]=O1.x*inv; av[5]=O1.y*inv; av[6]=O1.z*inv; av[7]=O1.w*inv;
    }
    short8 ah, al;
    #pragma unroll
    for (int i2 = 0; i2 < 8; i2++) { short h2, l2; bsplit(av[i2], h2, l2); ah[i2]=h2; al[i2]=l2; }
    #pragma unroll
    for (int g = 0; g < 4; g++) {
      short8 bh = *(const short8*)(Wh + (size_t)(g * 16 + r) * 128 + k0);
      short8 bl = *(const short8*)(Wl + (size_t)(g * 16 + r) * 128 + k0);
      acc[g] = __builtin_amdgcn_mfma_f32_16x16x32_bf16(al, bh, acc[g], 0, 0, 0);
      acc[g] = __builtin_amdgcn_mfma_f32_16x16x32_bf16(ah, bl, acc[g], 0, 0, 0);
      acc[g] = __builtin_amdgcn_mfma_f32_16x16x32_bf16(ah, bh, acc[g], 0, 0, 0);
    }
  }

  // park C-tile in LDS: Ls[row_local][col]
  #pragma unroll
  for (int g = 0; g < 4; g++)
    #pragma unroll
    for (int e = 0; e < 4; e++)
      Ls[w * 16 + quad * 4 + e][g * 16 + r] = acc[g][e];
  __syncthreads();

  // score phase. lane = row_local.
  float4 fr[16];
  #pragma unroll
  for (int e = 0; e < 16; e++) fr[e] = *(float4*)&Ls[lane][e * 4];

  float psc = 0.f;
  #pragma unroll
  for (int jj = 0; jj < 8; jj++) {
    const int j = w * 8 + jj;
    const float* wr = pw1 + j * 64;   // wave-uniform -> s_load
    float hj = pb1[j];
    #pragma unroll
    for (int e = 0; e < 16; e++) {
      float4 wv = ld4(wr + e * 4);
      hj += fr[e].x * wv.x + fr[e].y * wv.y + fr[e].z * wv.z + fr[e].w * wv.w;
    }
    float e2 = __expf(2.f * hj);
    psc += ((e2 - 1.f) / (e2 + 1.f)) * pw2[j];   // tanh via exp
  }
  partial[w][lane] = psc;
  __syncthreads();
  if (w == 0) {
    const int b = bx >> 4;
    float sc = pb2[0] + partial[0][lane] + partial[1][lane]
             + partial[2][lane] + partial[3][lane];
    float p = __expf(sc);
    #pragma unroll
    for (int e = 0; e < 16; e++) {
      Ls[lane][e*4+0] = p * fr[e].x; Ls[lane][e*4+1] = p * fr[e].y;
      Ls[lane][e*4+2] = p * fr[e].z; Ls[lane][e*4+3] = p * fr[e].w;
    }
    // single wave: DS ops in order, no barrier needed
    float colsum = 0.f;
    #pragma unroll 8
    for (int s = 0; s < 64; s++) colsum += Ls[s][lane];
    atomicAdd(&num[b * 64 + lane], colsum);
    float ps = p;
    #pragma unroll
    for (int off = 32; off > 0; off >>= 1)
      ps += __shfl_xor(ps, off, 64);
    if (lane == 0) atomicAdd(&den[b], ps);
  }

  // ---- last-block finalize (replaces the finalize dispatch)
  if (tid == 0) {
    __threadfence();                       // release: num/den atomics visible
    lastflag = (atomicAdd(cnt, 1u) == 255u) ? 1u : 0u;
  }
  __syncthreads();
  if (lastflag) {
    __threadfence();                       // acquire side
    for (int k = tid; k < 1024; k += 256) {
      float nv = __hip_atomic_load(&num[k], __ATOMIC_RELAXED, __HIP_MEMORY_SCOPE_AGENT);
      float dv = __hip_atomic_load(&den[k >> 6], __ATOMIC_RELAXED, __HIP_MEMORY_SCOPE_AGENT);
      out[k] = nv / dv;
    }
  }
}

extern "C" void kernel_launch(void* const* d_in, const int* in_sizes, int n_in,
                              void* d_out, int out_size, void* d_ws, size_t ws_size,
                              hipStream_t stream)
{
  const float* x          = (const float*)d_in[0];
  const float* proj_w     = (const float*)d_in[1];
  const float* proj_b     = (const float*)d_in[2];
  const float* loc_in_w   = (const float*)d_in[3];
  const float* loc_in_b   = (const float*)d_in[4];
  const float* loc_out_w  = (const float*)d_in[5];
  const float* loc_out_b  = (const float*)d_in[6];
  const float* glob_in_w  = (const float*)d_in[7];
  const float* glob_in_b  = (const float*)d_in[8];
  const float* glob_out_w = (const float*)d_in[9];
  const float* glob_out_b = (const float*)d_in[10];
  const float* fusion_w   = (const float*)d_in[11];
  const float* fusion_b   = (const float*)d_in[12];
  const float* pw1        = (const float*)d_in[13];
  const float* pb1        = (const float*)d_in[14];
  const float* pw2        = (const float*)d_in[15];
  const float* pb2        = (const float*)d_in[16];

  float* ws = (float*)d_ws;
  // Layout (float offsets):
  //  qkv_g    [0, 3145728)
  //  qkv_l    [4587520, 7733248)
  //  o_l      [7733248, 8781824)
  //  o_g      [8781824, 9830400)
  //  pl       [9830400, 9961472)
  //  KH/KL    shorts at 9961472 / 10141696 (360448 each)
  //  VTh/VTl  shorts at 10321920 / 10682368 (720896 each)
  //  bc       [11042816, 11042880)
  //  num/den/cnt [11042880, 11043921)
  //  wb       shorts at 11043921+ (112640)
  float* qkv_g = ws;
  float* qkv_l = ws + 4587520;
  float* o_l   = ws + 7733248;
  float* o_g   = ws + 8781824;
  float* pl    = ws + 9830400;
  short* KH    = (short*)(ws + 9961472);
  short* KL    = (short*)(ws + 10141696);
  short* VTh   = (short*)(ws + 10321920);
  short* VTl   = (short*)(ws + 10682368);
  float* bc    = ws + 11042816;
  float* numden= ws + 11042880;
  float* num   = numden;
  float* den   = numden + 1024;
  unsigned* cnt= (unsigned*)(numden + 1040);
  short* wb    = (short*)(ws + 11043921);
  short* projh = wb;           short* projl = wb + 20480;
  short* linh  = wb + 40960;   short* linl  = wb + 53248;
  short* ginh  = wb + 65536;   short* ginl  = wb + 77824;
  short* wfh   = wb + 90112;   short* wfl   = wb + 98304;
  float* out   = (float*)d_out;

  dim3 blk(256);
  // 1: weight split + fused fusion weights + combined bias + zeros + VT pads
  //    idx range = 53248 + 370688 = 423936 = 1656 * 256
  prep_w<<<1656, blk, 0, stream>>>(proj_w, loc_in_w, glob_in_w, fusion_w,
                                   loc_out_w, glob_out_w, loc_out_b, glob_out_b,
                                   fusion_b, wb, bc, numden, VTh, VTl);
  // 2: fused proj + qkv GEMM; writes qkv_l, qkv_g, KH/KL, VTh/VTl
  gemm_proj_qkv<<<256, blk, 0, stream>>>(
      x, projh, projl, proj_b, linh, linl, ginh, ginl, loc_in_b, glob_in_b,
      qkv_l, qkv_g, KH, KL, VTh, VTl);
  // 3: global MFMA attention (2048 blocks) + local attention (512 blocks)
  attn<<<2560, blk, 0, stream>>>(qkv_g, qkv_l, KH, KL, VTh, VTl, o_g, pl, o_l);
  // 4: fusion GEMM + score + pool partials + last-block finalize
  gemm_fuse_score<<<256, blk, 0, stream>>>(
      o_l, o_g, pl, qkv_g, wfh, wfl, bc, pw1, pb1, pw2, pb2, num, den, cnt, out);
}

// Round 9
// 180.160 us; speedup vs baseline: 3.3803x; 1.0032x over previous
//
#include <hip/hip_runtime.h>
#include <hip/hip_bf16.h>

// Shapes: B=16, S=1024, E=64, H=8, d=8, INPUT_DIM=310
// local mask: |i-j|<=5 (11 keys); sparse mask: j%3==0 or i==j (342 keys + diag)
//
// R19 = R14 exactly + ONLY the gemm_proj_qkv occupancy split (R16's 1024-block
// co-op version; R5 PMC showed the R14 version at 45us / 9.3% occupancy).
// attn = R14 (unpipelined, Pbuf[32]); fuse = R14 (256 blocks). Deconfounds
// R16 (which changed proj AND fuse together and regressed).
// Structure (4 dispatches):
//  1. prep_w        — weight split + fused fusion W + bc + numden/cnt + VT pads
//  2. gemm_proj_qkv — 1024 blocks; block = ONE 16-row tile, 4 co-op waves
//  3. attn          — global MFMA attention (2048) + local attention (512)
//  4. gemm_fuse_score (+ last-block finalize: out = num/den)
// GEMMs + global attention via mfma_f32_16x16x32_bf16, fp32 = hi+lo bf16 split.
// A-frag A[m=lane&15][k=quad*8+j]; B-frag B[n=lane&15][k=quad*8+j];
// C/D: col=lane&15, row=quad*4+reg.

typedef __attribute__((ext_vector_type(8))) short short8;
typedef __attribute__((ext_vector_type(4))) float float4v;

#define INV_SQRT8 0.3535533905932738f

__device__ __forceinline__ float4 ld4(const float* p) { return *(const float4*)p; }

__device__ __forceinline__ float4 f4fma(float s, float4 w, float4 a) {
  a.x = fmaf(s, w.x, a.x); a.y = fmaf(s, w.y, a.y);
  a.z = fmaf(s, w.z, a.z); a.w = fmaf(s, w.w, a.w);
  return a;
}

// fp32 -> bf16 via native converter (compiler emits v_cvt_pk_bf16_f32 path).
__device__ __forceinline__ short f2bf(float x) {
  __hip_bfloat16 b = __float2bfloat16(x);
  unsigned short u; __builtin_memcpy(&u, &b, 2);
  return (short)u;
}
__device__ __forceinline__ float bf2f(short s) {
  return __uint_as_float(((unsigned)(unsigned short)s) << 16);
}
// fp32 -> (bf16 hi, bf16 lo); lo = x - hi exact in fp32.
__device__ __forceinline__ void bsplit(float x, short& h, short& l) {
  h = f2bf(x);
  l = f2bf(x - bf2f(h));
}

// ---------------- prep_w: split weights + fused fusion weights + bc + zero
// num/den/cnt + VT constant pads (ones row n=8, zero rows n>8, kk>=342 pads).
__global__ __launch_bounds__(256) void prep_w(
    const float* __restrict__ pw, const float* __restrict__ liw,
    const float* __restrict__ giw, const float* __restrict__ fw,
    const float* __restrict__ low, const float* __restrict__ gow,
    const float* __restrict__ lob, const float* __restrict__ gob,
    const float* __restrict__ fb,
    short* __restrict__ wb, float* __restrict__ bc, float* __restrict__ numden,
    short* __restrict__ VTh, short* __restrict__ VTl)
{
  unsigned idx = blockIdx.x * 256 + threadIdx.x;
  if (idx < 53248u) {
    float v; unsigned ho, lo_;
    if (idx < 20480u) {           // proj, padded K 310->320
      unsigned r = idx / 320u, k = idx - r * 320u;
      v = (k < 310u) ? pw[r * 310u + k] : 0.f;
      ho = 0u + idx; lo_ = 20480u + idx;
    } else if (idx < 32768u) {    // loc_in
      unsigned i = idx - 20480u; v = liw[i]; ho = 40960u + i; lo_ = 53248u + i;
    } else if (idx < 45056u) {    // glob_in
      unsigned i = idx - 32768u; v = giw[i]; ho = 65536u + i; lo_ = 77824u + i;
    } else {                      // fused fusion weight W12[n][k]
      unsigned i = idx - 45056u;
      unsigned n = i >> 7, k = i & 127u;
      float s = 0.f;
      if (k < 64u) {
        for (int e = 0; e < 64; e++) s += fw[n * 128 + e] * low[e * 64 + k];
      } else {
        for (int e = 0; e < 64; e++) s += fw[n * 128 + 64 + e] * gow[e * 64 + (k - 64u)];
      }
      v = s; ho = 90112u + i; lo_ = 98304u + i;
    }
    short h, l; bsplit(v, h, l);
    wb[ho] = h; wb[lo_] = l;
    if (idx < 64u) {
      float b = fb[idx];
      for (int e = 0; e < 64; e++)
        b += lob[e] * fw[idx * 128 + e] + gob[e] * fw[idx * 128 + 64 + e];
      bc[idx] = b;
    }
    if (idx < 1041u) numden[idx] = 0.f;   // num[1024] + den[16] + cnt
  } else {
    // VT constant pads. Data rows (n<8, kk<342) come from gemm_proj_qkv.
    unsigned t = idx - 53248u;
    if (t < 370688u) {
      unsigned pos; short hv = 0;
      if (t < 360448u) {                // n in [8,16): ones row / zeros, 128 bh
        unsigned bh = t / 2816u;        // 8*352
        unsigned rem = t - bh * 2816u;
        unsigned n8 = rem / 352u;
        unsigned kk = rem - n8 * 352u;
        pos = (bh * 16u + 8u + n8) * 352u + kk;
        if (n8 == 0u) hv = (short)0x3F80;   // bf16(1.0)
      } else {                          // n<8, kk in [342,352): zero pad
        unsigned t2 = t - 360448u;      // < 10240
        unsigned bh = t2 / 80u;
        unsigned rem = t2 - bh * 80u;
        unsigned n = rem / 10u;
        unsigned kk = 342u + (rem - n * 10u);
        pos = (bh * 16u + n) * 352u + kk;
      }
      VTh[pos] = hv; VTl[pos] = 0;
    }
  }
}

// ---------------- fused proj + qkv GEMM, occupancy-split (R16 version).
// Grid 1024; block = ONE 16-row tile, 4 waves cooperate:
//   phase A: wave w computes proj col-frag g=w (16 cols); X A-loads duplicated
//            across waves (same addresses -> L1). xp -> LDS. barrier.
//   phase B: wave w -> branch br=w>>1, frag half hf=w&1 (6 frags), K=64.
//   epilogue: qkv halves; global-branch waves bsplit rows i%3==0 into KH/KL
//            and VTh/VTl straight from accumulators.
__global__ __launch_bounds__(256) void gemm_proj_qkv(
    const float* __restrict__ X,
    const short* __restrict__ PWh, const short* __restrict__ PWl,
    const float* __restrict__ pb,
    const short* __restrict__ LWh, const short* __restrict__ LWl,
    const short* __restrict__ GWh, const short* __restrict__ GWl,
    const float* __restrict__ lb, const float* __restrict__ gb,
    float* __restrict__ qkv_l, float* __restrict__ qkv_g,
    short* __restrict__ KH, short* __restrict__ KL,
    short* __restrict__ VTh, short* __restrict__ VTl)
{
  __shared__ __align__(16) short XPH[16][72];
  __shared__ __align__(16) short XPL[16][72];
  const int lane = threadIdx.x & 63;
  const int w = threadIdx.x >> 6;
  const int q = lane >> 4, r = lane & 15;
  const int m0 = blockIdx.x * 16;

  // ---- phase A: proj col-frag g = w
  float4v accp;
  {
    float bv = pb[w * 16 + r];
    float4v t = {bv, bv, bv, bv};
    accp = t;
  }
  const float* arow = X + (size_t)(m0 + r) * 310;
  #pragma unroll
  for (int ks = 0; ks < 10; ks++) {
    const int k0 = ks * 32 + q * 8;
    float av[8];
    if (ks < 9) {
      const float* ap = arow + k0;
      #pragma unroll
      for (int t = 0; t < 4; t++) {
        float2 f = *(const float2*)(ap + t * 2);
        av[t*2] = f.x; av[t*2+1] = f.y;
      }
    } else {
      #pragma unroll
      for (int j = 0; j < 8; j++) {
        int kidx = k0 + j;
        av[j] = (kidx < 310) ? arow[kidx] : 0.f;
      }
    }
    short8 ah, al;
    #pragma unroll
    for (int i = 0; i < 8; i++) { short h, l; bsplit(av[i], h, l); ah[i]=h; al[i]=l; }
    short8 bh = *(const short8*)(PWh + (size_t)(w * 16 + r) * 320 + k0);
    short8 bl = *(const short8*)(PWl + (size_t)(w * 16 + r) * 320 + k0);
    accp = __builtin_amdgcn_mfma_f32_16x16x32_bf16(al, bh, accp, 0, 0, 0);
    accp = __builtin_amdgcn_mfma_f32_16x16x32_bf16(ah, bl, accp, 0, 0, 0);
    accp = __builtin_amdgcn_mfma_f32_16x16x32_bf16(ah, bh, accp, 0, 0, 0);
  }
  // xp frag -> LDS bf16 hi/lo (cross-wave consumers -> barrier below)
  #pragma unroll
  for (int e = 0; e < 4; e++) {
    short h, l; bsplit(accp[e], h, l);
    XPH[q * 4 + e][w * 16 + r] = h;
    XPL[q * 4 + e][w * 16 + r] = l;
  }
  __syncthreads();

  // ---- phase B: branch br, frag half hf
  const int br = w >> 1, hf = w & 1;
  const short* Wh = br ? GWh : LWh;
  const short* Wl = br ? GWl : LWl;
  const float* bb = br ? gb : lb;
  float* qkv = br ? qkv_g : qkv_l;

  float4v acc[6];
  #pragma unroll
  for (int j = 0; j < 6; j++) {
    float bv = bb[(hf * 6 + j) * 16 + r];
    float4v t = {bv, bv, bv, bv};
    acc[j] = t;
  }
  #pragma unroll
  for (int ks = 0; ks < 2; ks++) {
    const int k0 = ks * 32 + q * 8;
    short8 ah = *(const short8*)&XPH[r][k0];
    short8 al = *(const short8*)&XPL[r][k0];
    #pragma unroll
    for (int j = 0; j < 6; j++) {
      const int nf = hf * 6 + j;
      short8 bh = *(const short8*)(Wh + (size_t)(nf * 16 + r) * 64 + k0);
      short8 bl = *(const short8*)(Wl + (size_t)(nf * 16 + r) * 64 + k0);
      acc[j] = __builtin_amdgcn_mfma_f32_16x16x32_bf16(al, bh, acc[j], 0, 0, 0);
      acc[j] = __builtin_amdgcn_mfma_f32_16x16x32_bf16(ah, bl, acc[j], 0, 0, 0);
      acc[j] = __builtin_amdgcn_mfma_f32_16x16x32_bf16(ah, bh, acc[j], 0, 0, 0);
    }
  }

  // ---- epilogue
  const int b = m0 >> 10;           // 16-row blocks never straddle a batch
  const int bh8 = b * 8;
  #pragma unroll
  for (int e = 0; e < 4; e++) {
    const int row = m0 + q * 4 + e;
    const int i = row & 1023;
    #pragma unroll
    for (int j = 0; j < 6; j++) {
      const int nf = hf * 6 + j;
      qkv[(size_t)row * 192 + nf * 16 + r] = acc[j][e];
    }
    if (br == 1 && i % 3 == 0) {
      const int kk = i / 3;         // 0..341
      #pragma unroll
      for (int j = 0; j < 6; j++) {
        const int nf = hf * 6 + j;
        if (nf >= 4) {
          const int col = nf * 16 + r;        // 64..191
          float v = acc[j][e];
          short h, l; bsplit(v, h, l);
          if (col < 128) {                    // K rows
            const int ck = col - 64;
            const int hh = ck >> 3, d = ck & 7;
            KH[(size_t)(bh8 + hh) * 2816 + kk * 8 + d] = h;
            KL[(size_t)(bh8 + hh) * 2816 + kk * 8 + d] = l;
          } else {                            // V^T rows
            const int cv = col - 128;
            const int hh = cv >> 3, d = cv & 7;
            VTh[((size_t)(bh8 + hh) * 16 + d) * 352 + kk] = h;
            VTl[((size_t)(bh8 + hh) * 16 + d) * 352 + kk] = l;
          }
        }
      }
    }
  }
}

// ---------------- attention (R14 version): blocks [0,2048) = MFMA global
// attention, blocks [2048,2560) = local sliding-window (independent work).
// KH pads kk>=342 poison — safe (p forced to 0 by key<342 mask).
__global__ __launch_bounds__(256) void attn(
    const float* __restrict__ qkv_g, const float* __restrict__ qkv_l,
    const short* __restrict__ KH, const short* __restrict__ KL,
    const short* __restrict__ VTh, const short* __restrict__ VTl,
    float* __restrict__ o_g, float* __restrict__ pl, float* __restrict__ o_l)
{
  __shared__ short Pbuf[4][2][2][16][32];   // wave, parity, hi/lo, q, k
  const int u = blockIdx.x;
  if (u < 2048) {
    const int qt = u & 15, h = (u >> 4) & 7, b = u >> 7;
    const int w = threadIdx.x >> 6, lane = threadIdx.x & 63;
    const int quad = lane >> 4, r = lane & 15;
    const int bh = b * 8 + h;
    const int m0 = qt * 64 + w * 16;

    const short8 z8 = {0,0,0,0,0,0,0,0};
    short8 qh = z8, ql = z8;
    if (quad == 0) {
      const float* qp = qkv_g + (size_t)(b * 1024 + m0 + r) * 192 + h * 8;
      float4 a0 = ld4(qp), a1 = ld4(qp + 4);
      float qv[8] = {a0.x, a0.y, a0.z, a0.w, a1.x, a1.y, a1.z, a1.w};
      #pragma unroll
      for (int d = 0; d < 8; d++) { short hh, ll; bsplit(qv[d], hh, ll); qh[d]=hh; ql[d]=ll; }
    }
    const short* kbase  = KH + (size_t)bh * 2816;
    const short* klbase = KL + (size_t)bh * 2816;
    const short* vhbase = VTh + ((size_t)bh * 16 + r) * 352;
    const short* vlbase = VTl + ((size_t)bh * 16 + r) * 352;

    float4v oacc = {0.f, 0.f, 0.f, 0.f};

    for (int kc = 0; kc < 11; kc++) {
      short8 kh0 = z8, kl0 = z8, kh1 = z8, kl1 = z8;
      if (quad == 0) {
        kh0 = *(const short8*)(kbase  + (size_t)(kc * 32 + r) * 8);
        kl0 = *(const short8*)(klbase + (size_t)(kc * 32 + r) * 8);
        kh1 = *(const short8*)(kbase  + (size_t)(kc * 32 + 16 + r) * 8);
        kl1 = *(const short8*)(klbase + (size_t)(kc * 32 + 16 + r) * 8);
      }
      float4v s0 = {0.f,0.f,0.f,0.f}, s1 = {0.f,0.f,0.f,0.f};
      s0 = __builtin_amdgcn_mfma_f32_16x16x32_bf16(qh, kl0, s0, 0, 0, 0);
      s0 = __builtin_amdgcn_mfma_f32_16x16x32_bf16(ql, kh0, s0, 0, 0, 0);
      s0 = __builtin_amdgcn_mfma_f32_16x16x32_bf16(qh, kh0, s0, 0, 0, 0);
      s1 = __builtin_amdgcn_mfma_f32_16x16x32_bf16(qh, kl1, s1, 0, 0, 0);
      s1 = __builtin_amdgcn_mfma_f32_16x16x32_bf16(ql, kh1, s1, 0, 0, 0);
      s1 = __builtin_amdgcn_mfma_f32_16x16x32_bf16(qh, kh1, s1, 0, 0, 0);

      const int par = kc & 1;
      const int key0 = kc * 32 + r, key1 = key0 + 16;
      #pragma unroll
      for (int e = 0; e < 4; e++) {
        float p0 = (key0 < 342) ? __expf(s0[e] * INV_SQRT8) : 0.f;
        float p1 = (key1 < 342) ? __expf(s1[e] * INV_SQRT8) : 0.f;
        short h0, l0, h1, l1; bsplit(p0, h0, l0); bsplit(p1, h1, l1);
        const int qloc = quad * 4 + e;
        Pbuf[w][par][0][qloc][r]      = h0;
        Pbuf[w][par][0][qloc][16 + r] = h1;
        Pbuf[w][par][1][qloc][r]      = l0;
        Pbuf[w][par][1][qloc][16 + r] = l1;
      }
      // Same-wave LDS transpose read (DS ops in-order per wave; no barrier).
      short8 pA = *(const short8*)&Pbuf[w][par][0][r][quad * 8];
      short8 pB = *(const short8*)&Pbuf[w][par][1][r][quad * 8];
      short8 vh = *(const short8*)(vhbase + kc * 32 + quad * 8);
      short8 vl = *(const short8*)(vlbase + kc * 32 + quad * 8);
      oacc = __builtin_amdgcn_mfma_f32_16x16x32_bf16(pA, vl, oacc, 0, 0, 0);
      oacc = __builtin_amdgcn_mfma_f32_16x16x32_bf16(pB, vh, oacc, 0, 0, 0);
      oacc = __builtin_amdgcn_mfma_f32_16x16x32_bf16(pA, vh, oacc, 0, 0, 0);
    }

    #pragma unroll
    for (int e = 0; e < 4; e++) {
      const int orow = b * 1024 + m0 + quad * 4 + e;
      if (r < 8)       o_g[(size_t)orow * 64 + h * 8 + r] = oacc[e];
      else if (r == 8) pl[(size_t)orow * 8 + h] = oacc[e];
    }
  } else {
    int t = (u - 2048) * 256 + threadIdx.x;   // 131072
    int h = t & 7;
    int i = (t >> 3) & 1023;
    int b = t >> 13;
    const float* base = qkv_l + (size_t)b * 1024 * 192;
    const float* qp = base + (size_t)i * 192 + h * 8;
    float4 q0 = ld4(qp), q1 = ld4(qp + 4);
    float l = 0.f;
    float4 o0 = make_float4(0.f, 0.f, 0.f, 0.f);
    float4 o1 = make_float4(0.f, 0.f, 0.f, 0.f);
    int jlo = i - 5; if (jlo < 0) jlo = 0;
    int jhi = i + 5; if (jhi > 1023) jhi = 1023;
    for (int j = jlo; j <= jhi; j++) {
      const float* kp = base + (size_t)j * 192 + 64 + h * 8;
      float4 k0 = ld4(kp), k1 = ld4(kp + 4);
      float s = q0.x * k0.x + q0.y * k0.y + q0.z * k0.z + q0.w * k0.w
              + q1.x * k1.x + q1.y * k1.y + q1.z * k1.z + q1.w * k1.w;
      float p = __expf(s * INV_SQRT8);
      l += p;
      float4 v0 = ld4(kp + 64), v1 = ld4(kp + 68);
      o0 = f4fma(p, v0, o0);
      o1 = f4fma(p, v1, o1);
    }
    float inv = 1.f / l;
    float* op = o_l + (size_t)(b * 1024 + i) * 64 + h * 8;
    float4 r0, r1;
    r0.x = o0.x * inv; r0.y = o0.y * inv; r0.z = o0.z * inv; r0.w = o0.w * inv;
    r1.x = o1.x * inv; r1.y = o1.y * inv; r1.z = o1.z * inv; r1.w = o1.w * inv;
    *(float4*)op = r0;
    *(float4*)(op + 4) = r1;
  }
}

// ---------------- Fusion GEMM + score + pool partials (R14 version).
// Block = 64 rows (grid 256). Wave w: rows w*16..+16, ALL 64 cols (4 frags).
// Diag-key + 1/l normalization folded into A-load. Last block finalizes.
__global__ __launch_bounds__(256) void gemm_fuse_score(
    const float* __restrict__ o_l, const float* __restrict__ o_g,
    const float* __restrict__ pl, const float* __restrict__ qkv_g,
    const short* __restrict__ Wh, const short* __restrict__ Wl,
    const float* __restrict__ bc,
    const float* __restrict__ pw1, const float* __restrict__ pb1,
    const float* __restrict__ pw2, const float* __restrict__ pb2,
    float* __restrict__ num, float* __restrict__ den,
    unsigned* __restrict__ cnt, float* __restrict__ out)
{
  __shared__ float Ls[64][68];
  __shared__ float partial[4][64];
  __shared__ unsigned lastflag;
  const int tid = threadIdx.x;
  const int lane = tid & 63, w = tid >> 6;
  const int quad = lane >> 4, r = lane & 15;
  const int bx = blockIdx.x;
  const int m0 = bx * 64 + w * 16;

  float4v acc[4];
  #pragma unroll
  for (int g = 0; g < 4; g++) {
    float bv = bc[g * 16 + r];
    float4v t = {bv, bv, bv, bv};
    acc[g] = t;
  }

  #pragma unroll
  for (int ks = 0; ks < 4; ks++) {
    const int k0 = ks * 32 + quad * 8;
    const int row = m0 + r;
    float av[8];
    if (ks < 2) {   // local branch, already normalized
      const float* ap = o_l + (size_t)row * 64 + k0;
      float4 f0 = ld4(ap), f1 = ld4(ap + 4);
      av[0]=f0.x; av[1]=f0.y; av[2]=f0.z; av[3]=f0.w;
      av[4]=f1.x; av[5]=f1.y; av[6]=f1.z; av[7]=f1.w;
    } else {        // global branch: unnormalized O + diag + normalize
      const int off = k0 - 64;
      const int h = off >> 3;
      const float* op = o_g + (size_t)row * 64 + off;
      float4 O0 = ld4(op), O1 = ld4(op + 4);
      float l = pl[(size_t)row * 8 + h];
      const int i = row & 1023;
      if (i % 3 != 0) {
        const float* base = qkv_g + (size_t)row * 192;
        const float* qp = base + h * 8;
        const float* kpp = base + 64 + h * 8;
        const float* vp = base + 128 + h * 8;
        float4 q0 = ld4(qp), q1 = ld4(qp + 4);
        float4 k0v = ld4(kpp), k1v = ld4(kpp + 4);
        float s = q0.x*k0v.x + q0.y*k0v.y + q0.z*k0v.z + q0.w*k0v.w
                + q1.x*k1v.x + q1.y*k1v.y + q1.z*k1v.z + q1.w*k1v.w;
        float p = __expf(s * INV_SQRT8);
        float4 v0 = ld4(vp), v1 = ld4(vp + 4);
        O0 = f4fma(p, v0, O0); O1 = f4fma(p, v1, O1);
        l += p;
      }
      float inv = 1.f / l;
      av[0]=O0.x*inv; av[1]=O0.y*inv; av[2]=O0.z*inv; av[3]=O0.w*inv;
      av[4]=O1.x*inv; av[5]=O1.y*inv; av[6]=O1.z*inv; av[7]=O1.w*inv;
    }
    short8 ah, al;
    #pragma unroll
    for (int i2 = 0; i2 < 8; i2++) { short h2, l2; bsplit(av[i2], h2, l2); ah[i2]=h2; al[i2]=l2; }
    #pragma unroll
    for (int g = 0; g < 4; g++) {
      short8 bh = *(const short8*)(Wh + (size_t)(g * 16 + r) * 128 + k0);
      short8 bl = *(const short8*)(Wl + (size_t)(g * 16 + r) * 128 + k0);
      acc[g] = __builtin_amdgcn_mfma_f32_16x16x32_bf16(al, bh, acc[g], 0, 0, 0);
      acc[g] = __builtin_amdgcn_mfma_f32_16x16x32_bf16(ah, bl, acc[g], 0, 0, 0);
      acc[g] = __builtin_amdgcn_mfma_f32_16x16x32_bf16(ah, bh, acc[g], 0, 0, 0);
    }
  }

  // park C-tile in LDS: Ls[row_local][col]
  #pragma unroll
  for (int g = 0; g < 4; g++)
    #pragma unroll
    for (int e = 0; e < 4; e++)
      Ls[w * 16 + quad * 4 + e][g * 16 + r] = acc[g][e];
  __syncthreads();

  // score phase. lane = row_local.
  float4 fr[16];
  #pragma unroll
  for (int e = 0; e < 16; e++) fr[e] = *(float4*)&Ls[lane][e * 4];

  float psc = 0.f;
  #pragma unroll
  for (int jj = 0; jj < 8; jj++) {
    const int j = w * 8 + jj;
    const float* wr = pw1 + j * 64;   // wave-uniform -> s_load
    float hj = pb1[j];
    #pragma unroll
    for (int e = 0; e < 16; e++) {
      float4 wv = ld4(wr + e * 4);
      hj += fr[e].x * wv.x + fr[e].y * wv.y + fr[e].z * wv.z + fr[e].w * wv.w;
    }
    float e2 = __expf(2.f * hj);
    psc += ((e2 - 1.f) / (e2 + 1.f)) * pw2[j];   // tanh via exp
  }
  partial[w][lane] = psc;
  __syncthreads();
  if (w == 0) {
    const int b = bx >> 4;
    float sc = pb2[0] + partial[0][lane] + partial[1][lane]
             + partial[2][lane] + partial[3][lane];
    float p = __expf(sc);
    #pragma unroll
    for (int e = 0; e < 16; e++) {
      Ls[lane][e*4+0] = p * fr[e].x; Ls[lane][e*4+1] = p * fr[e].y;
      Ls[lane][e*4+2] = p * fr[e].z; Ls[lane][e*4+3] = p * fr[e].w;
    }
    // single wave: DS ops in order, no barrier needed
    float colsum = 0.f;
    #pragma unroll 8
    for (int s = 0; s < 64; s++) colsum += Ls[s][lane];
    atomicAdd(&num[b * 64 + lane], colsum);
    float ps = p;
    #pragma unroll
    for (int off = 32; off > 0; off >>= 1)
      ps += __shfl_xor(ps, off, 64);
    if (lane == 0) atomicAdd(&den[b], ps);
  }

  // ---- last-block finalize (replaces the finalize dispatch)
  if (tid == 0) {
    __threadfence();                       // release: num/den atomics visible
    lastflag = (atomicAdd(cnt, 1u) == 255u) ? 1u : 0u;
  }
  __syncthreads();
  if (lastflag) {
    __threadfence();                       // acquire side
    for (int k = tid; k < 1024; k += 256) {
      float nv = __hip_atomic_load(&num[k], __ATOMIC_RELAXED, __HIP_MEMORY_SCOPE_AGENT);
      float dv = __hip_atomic_load(&den[k >> 6], __ATOMIC_RELAXED, __HIP_MEMORY_SCOPE_AGENT);
      out[k] = nv / dv;
    }
  }
}

extern "C" void kernel_launch(void* const* d_in, const int* in_sizes, int n_in,
                              void* d_out, int out_size, void* d_ws, size_t ws_size,
                              hipStream_t stream)
{
  const float* x          = (const float*)d_in[0];
  const float* proj_w     = (const float*)d_in[1];
  const float* proj_b     = (const float*)d_in[2];
  const float* loc_in_w   = (const float*)d_in[3];
  const float* loc_in_b   = (const float*)d_in[4];
  const float* loc_out_w  = (const float*)d_in[5];
  const float* loc_out_b  = (const float*)d_in[6];
  const float* glob_in_w  = (const float*)d_in[7];
  const float* glob_in_b  = (const float*)d_in[8];
  const float* glob_out_w = (const float*)d_in[9];
  const float* glob_out_b = (const float*)d_in[10];
  const float* fusion_w   = (const float*)d_in[11];
  const float* fusion_b   = (const float*)d_in[12];
  const float* pw1        = (const float*)d_in[13];
  const float* pb1        = (const float*)d_in[14];
  const float* pw2        = (const float*)d_in[15];
  const float* pb2        = (const float*)d_in[16];

  float* ws = (float*)d_ws;
  // Layout (float offsets):
  //  qkv_g    [0, 3145728)
  //  qkv_l    [4587520, 7733248)
  //  o_l      [7733248, 8781824)
  //  o_g      [8781824, 9830400)
  //  pl       [9830400, 9961472)
  //  KH/KL    shorts at 9961472 / 10141696 (360448 each)
  //  VTh/VTl  shorts at 10321920 / 10682368 (720896 each)
  //  bc       [11042816, 11042880)
  //  num/den/cnt [11042880, 11043921)
  //  wb       shorts at 11043921+ (112640)
  float* qkv_g = ws;
  float* qkv_l = ws + 4587520;
  float* o_l   = ws + 7733248;
  float* o_g   = ws + 8781824;
  float* pl    = ws + 9830400;
  short* KH    = (short*)(ws + 9961472);
  short* KL    = (short*)(ws + 10141696);
  short* VTh   = (short*)(ws + 10321920);
  short* VTl   = (short*)(ws + 10682368);
  float* bc    = ws + 11042816;
  float* numden= ws + 11042880;
  float* num   = numden;
  float* den   = numden + 1024;
  unsigned* cnt= (unsigned*)(numden + 1040);
  short* wb    = (short*)(ws + 11043921);
  short* projh = wb;           short* projl = wb + 20480;
  short* linh  = wb + 40960;   short* linl  = wb + 53248;
  short* ginh  = wb + 65536;   short* ginl  = wb + 77824;
  short* wfh   = wb + 90112;   short* wfl   = wb + 98304;
  float* out   = (float*)d_out;

  dim3 blk(256);
  // 1: weight split + fused fusion weights + combined bias + zeros + VT pads
  //    idx range = 53248 + 370688 = 423936 = 1656 * 256
  prep_w<<<1656, blk, 0, stream>>>(proj_w, loc_in_w, glob_in_w, fusion_w,
                                   loc_out_w, glob_out_w, loc_out_b, glob_out_b,
                                   fusion_b, wb, bc, numden, VTh, VTl);
  // 2: fused proj + qkv GEMM; 1024 blocks (one 16-row tile, 4 co-op waves)
  gemm_proj_qkv<<<1024, blk, 0, stream>>>(
      x, projh, projl, proj_b, linh, linl, ginh, ginl, loc_in_b, glob_in_b,
      qkv_l, qkv_g, KH, KL, VTh, VTl);
  // 3: global MFMA attention (2048 blocks) + local attention (512 blocks)
  attn<<<2560, blk, 0, stream>>>(qkv_g, qkv_l, KH, KL, VTh, VTl, o_g, pl, o_l);
  // 4: fusion GEMM + score + pool partials + last-block finalize
  gemm_fuse_score<<<256, blk, 0, stream>>>(
      o_l, o_g, pl, qkv_g, wfh, wfl, bc, pw1, pb1, pw2, pb2, num, den, cnt, out);
}

// Round 10
// 177.774 us; speedup vs baseline: 3.4257x; 1.0134x over previous
//
#include <hip/hip_runtime.h>
#include <hip/hip_bf16.h>

// Shapes: B=16, S=1024, E=64, H=8, d=8, INPUT_DIM=310
// local mask: |i-j|<=5 (11 keys); sparse mask: j%3==0 or i==j (342 keys + diag)
//
// R20 = R14 exactly (best measured config: 4 dispatches, 64-row proj+qkv,
// R14 attn, 256-block fuse+finalize) + prep_w trimmed: VT pad rows n in
// [9,16) are provably never consumed (their MFMA output columns land in
// lanes r in [9,16), which are never written back; MFMA columns are
// lane-independent), so only the n=8 ones-row and the kk>=342 pads of rows
// n<=8 are initialized. prep grid 1656 -> 424 blocks.
// Structure (4 dispatches):
//  1. prep_w        — weight split + fused fusion W + bc + numden/cnt + VT pads
//  2. gemm_proj_qkv — proj GEMM -> xp in LDS (bf16 hi/lo) -> qkv GEMM both
//                     branches; epilogue writes qkv fp32 AND K/V bf16 buffers
//  3. attn          — global MFMA attention (2048) + local attention (512)
//  4. gemm_fuse_score (+ last-block finalize: out = num/den)
// GEMMs + global attention via mfma_f32_16x16x32_bf16, fp32 = hi+lo bf16 split.
// A-frag A[m=lane&15][k=quad*8+j]; B-frag B[n=lane&15][k=quad*8+j];
// C/D: col=lane&15, row=quad*4+reg.

typedef __attribute__((ext_vector_type(8))) short short8;
typedef __attribute__((ext_vector_type(4))) float float4v;

#define INV_SQRT8 0.3535533905932738f

__device__ __forceinline__ float4 ld4(const float* p) { return *(const float4*)p; }

__device__ __forceinline__ float4 f4fma(float s, float4 w, float4 a) {
  a.x = fmaf(s, w.x, a.x); a.y = fmaf(s, w.y, a.y);
  a.z = fmaf(s, w.z, a.z); a.w = fmaf(s, w.w, a.w);
  return a;
}

// fp32 -> bf16 via native converter (compiler emits v_cvt_pk_bf16_f32 path).
__device__ __forceinline__ short f2bf(float x) {
  __hip_bfloat16 b = __float2bfloat16(x);
  unsigned short u; __builtin_memcpy(&u, &b, 2);
  return (short)u;
}
__device__ __forceinline__ float bf2f(short s) {
  return __uint_as_float(((unsigned)(unsigned short)s) << 16);
}
// fp32 -> (bf16 hi, bf16 lo); lo = x - hi exact in fp32.
__device__ __forceinline__ void bsplit(float x, short& h, short& l) {
  h = f2bf(x);
  l = f2bf(x - bf2f(h));
}

// ---------------- prep_w: split weights + fused fusion weights + bc + zero
// num/den/cnt + REQUIRED VT constant pads only:
//  idx map: [0,53248) weights; [53248,53248+45056) VT n=8 ones row (128 bh
//  panels x 352); next 10240 = VT n<8, kk in [342,352) zero pads.
//  (VT rows n in [9,16) stay poisoned — never consumed, see header.)
__global__ __launch_bounds__(256) void prep_w(
    const float* __restrict__ pw, const float* __restrict__ liw,
    const float* __restrict__ giw, const float* __restrict__ fw,
    const float* __restrict__ low, const float* __restrict__ gow,
    const float* __restrict__ lob, const float* __restrict__ gob,
    const float* __restrict__ fb,
    short* __restrict__ wb, float* __restrict__ bc, float* __restrict__ numden,
    short* __restrict__ VTh, short* __restrict__ VTl)
{
  unsigned idx = blockIdx.x * 256 + threadIdx.x;
  if (idx < 53248u) {
    float v; unsigned ho, lo_;
    if (idx < 20480u) {           // proj, padded K 310->320
      unsigned r = idx / 320u, k = idx - r * 320u;
      v = (k < 310u) ? pw[r * 310u + k] : 0.f;
      ho = 0u + idx; lo_ = 20480u + idx;
    } else if (idx < 32768u) {    // loc_in
      unsigned i = idx - 20480u; v = liw[i]; ho = 40960u + i; lo_ = 53248u + i;
    } else if (idx < 45056u) {    // glob_in
      unsigned i = idx - 32768u; v = giw[i]; ho = 65536u + i; lo_ = 77824u + i;
    } else {                      // fused fusion weight W12[n][k]
      unsigned i = idx - 45056u;
      unsigned n = i >> 7, k = i & 127u;
      float s = 0.f;
      if (k < 64u) {
        for (int e = 0; e < 64; e++) s += fw[n * 128 + e] * low[e * 64 + k];
      } else {
        for (int e = 0; e < 64; e++) s += fw[n * 128 + 64 + e] * gow[e * 64 + (k - 64u)];
      }
      v = s; ho = 90112u + i; lo_ = 98304u + i;
    }
    short h, l; bsplit(v, h, l);
    wb[ho] = h; wb[lo_] = l;
    if (idx < 64u) {
      float b = fb[idx];
      for (int e = 0; e < 64; e++)
        b += lob[e] * fw[idx * 128 + e] + gob[e] * fw[idx * 128 + 64 + e];
      bc[idx] = b;
    }
    if (idx < 1041u) numden[idx] = 0.f;   // num[1024] + den[16] + cnt
  } else {
    // Required VT constant pads only.
    unsigned t = idx - 53248u;
    if (t < 55296u) {
      unsigned pos; short hv;
      if (t < 45056u) {                 // n=8 ones row, 128 bh panels
        unsigned bh = t / 352u;
        unsigned kk = t - bh * 352u;
        pos = (bh * 16u + 8u) * 352u + kk;
        hv = (short)0x3F80;             // bf16(1.0)
      } else {                          // n<8, kk in [342,352): zero pad
        unsigned t2 = t - 45056u;       // < 10240
        unsigned bh = t2 / 80u;
        unsigned rem = t2 - bh * 80u;
        unsigned n = rem / 10u;
        unsigned kk = 342u + (rem - n * 10u);
        pos = (bh * 16u + n) * 352u + kk;
        hv = 0;
      }
      VTh[pos] = hv; VTl[pos] = 0;
    }
  }
}

// ---------------- fused proj + qkv GEMM (R14 64-row block version).
__global__ __launch_bounds__(256) void gemm_proj_qkv(
    const float* __restrict__ X,
    const short* __restrict__ PWh, const short* __restrict__ PWl,
    const float* __restrict__ pb,
    const short* __restrict__ LWh, const short* __restrict__ LWl,
    const short* __restrict__ GWh, const short* __restrict__ GWl,
    const float* __restrict__ lb, const float* __restrict__ gb,
    float* __restrict__ qkv_l, float* __restrict__ qkv_g,
    short* __restrict__ KH, short* __restrict__ KL,
    short* __restrict__ VTh, short* __restrict__ VTl)
{
  __shared__ __align__(16) short XPH[64][72];
  __shared__ __align__(16) short XPL[64][72];
  const int lane = threadIdx.x & 63;
  const int w = threadIdx.x >> 6;
  const int q = lane >> 4, r = lane & 15;
  const int mloc = w * 16;
  const int m0 = blockIdx.x * 64 + mloc;

  // ---- phase A: proj
  float4v accp[4];
  #pragma unroll
  for (int g = 0; g < 4; g++) {
    float bv = pb[g * 16 + r];
    float4v t = {bv, bv, bv, bv};
    accp[g] = t;
  }
  const float* arow = X + (size_t)(m0 + r) * 310;
  #pragma unroll
  for (int ks = 0; ks < 10; ks++) {
    const int k0 = ks * 32 + q * 8;
    float av[8];
    if (ks < 9) {
      const float* ap = arow + k0;
      #pragma unroll
      for (int t = 0; t < 4; t++) {
        float2 f = *(const float2*)(ap + t * 2);
        av[t*2] = f.x; av[t*2+1] = f.y;
      }
    } else {
      #pragma unroll
      for (int j = 0; j < 8; j++) {
        int kidx = k0 + j;
        av[j] = (kidx < 310) ? arow[kidx] : 0.f;
      }
    }
    short8 ah, al;
    #pragma unroll
    for (int i = 0; i < 8; i++) { short h, l; bsplit(av[i], h, l); ah[i]=h; al[i]=l; }
    #pragma unroll
    for (int g = 0; g < 4; g++) {
      short8 bh = *(const short8*)(PWh + (size_t)(g * 16 + r) * 320 + k0);
      short8 bl = *(const short8*)(PWl + (size_t)(g * 16 + r) * 320 + k0);
      accp[g] = __builtin_amdgcn_mfma_f32_16x16x32_bf16(al, bh, accp[g], 0, 0, 0);
      accp[g] = __builtin_amdgcn_mfma_f32_16x16x32_bf16(ah, bl, accp[g], 0, 0, 0);
      accp[g] = __builtin_amdgcn_mfma_f32_16x16x32_bf16(ah, bh, accp[g], 0, 0, 0);
    }
  }
  // xp tile -> LDS bf16 hi/lo (wave-local rows => no barrier)
  #pragma unroll
  for (int g = 0; g < 4; g++)
    #pragma unroll
    for (int e = 0; e < 4; e++) {
      short h, l; bsplit(accp[g][e], h, l);
      XPH[mloc + q * 4 + e][g * 16 + r] = h;
      XPL[mloc + q * 4 + e][g * 16 + r] = l;
    }

  // ---- phase B: qkv both branches, K=64
  float4v acc[2][12];
  #pragma unroll
  for (int nf = 0; nf < 12; nf++) {
    float bv0 = lb[nf * 16 + r], bv1 = gb[nf * 16 + r];
    float4v t0 = {bv0, bv0, bv0, bv0};
    float4v t1 = {bv1, bv1, bv1, bv1};
    acc[0][nf] = t0; acc[1][nf] = t1;
  }
  #pragma unroll
  for (int ks = 0; ks < 2; ks++) {
    const int k0 = ks * 32 + q * 8;
    short8 ah = *(const short8*)&XPH[mloc + r][k0];
    short8 al = *(const short8*)&XPL[mloc + r][k0];
    #pragma unroll
    for (int nf = 0; nf < 12; nf++) {
      short8 bh0 = *(const short8*)(LWh + (size_t)(nf * 16 + r) * 64 + k0);
      short8 bl0 = *(const short8*)(LWl + (size_t)(nf * 16 + r) * 64 + k0);
      acc[0][nf] = __builtin_amdgcn_mfma_f32_16x16x32_bf16(al, bh0, acc[0][nf], 0, 0, 0);
      acc[0][nf] = __builtin_amdgcn_mfma_f32_16x16x32_bf16(ah, bl0, acc[0][nf], 0, 0, 0);
      acc[0][nf] = __builtin_amdgcn_mfma_f32_16x16x32_bf16(ah, bh0, acc[0][nf], 0, 0, 0);
      short8 bh1 = *(const short8*)(GWh + (size_t)(nf * 16 + r) * 64 + k0);
      short8 bl1 = *(const short8*)(GWl + (size_t)(nf * 16 + r) * 64 + k0);
      acc[1][nf] = __builtin_amdgcn_mfma_f32_16x16x32_bf16(al, bh1, acc[1][nf], 0, 0, 0);
      acc[1][nf] = __builtin_amdgcn_mfma_f32_16x16x32_bf16(ah, bl1, acc[1][nf], 0, 0, 0);
      acc[1][nf] = __builtin_amdgcn_mfma_f32_16x16x32_bf16(ah, bh1, acc[1][nf], 0, 0, 0);
    }
  }

  // ---- epilogue
  const int b = m0 >> 10;           // 64-row blocks never straddle a batch
  const int bh8 = b * 8;
  #pragma unroll
  for (int e = 0; e < 4; e++) {
    const int row = m0 + q * 4 + e;
    const int i = row & 1023;
    #pragma unroll
    for (int nf = 0; nf < 12; nf++) {
      qkv_l[(size_t)row * 192 + nf * 16 + r] = acc[0][nf][e];
      qkv_g[(size_t)row * 192 + nf * 16 + r] = acc[1][nf][e];
    }
    if (i % 3 == 0) {
      const int kk = i / 3;         // 0..341
      #pragma unroll
      for (int nf = 4; nf < 12; nf++) {
        const int col = nf * 16 + r;        // 64..191
        float v = acc[1][nf][e];
        short h, l; bsplit(v, h, l);
        if (col < 128) {                    // K rows
          const int ck = col - 64;
          const int hh = ck >> 3, d = ck & 7;
          KH[(size_t)(bh8 + hh) * 2816 + kk * 8 + d] = h;
          KL[(size_t)(bh8 + hh) * 2816 + kk * 8 + d] = l;
        } else {                            // V^T rows
          const int cv = col - 128;
          const int hh = cv >> 3, d = cv & 7;
          VTh[((size_t)(bh8 + hh) * 16 + d) * 352 + kk] = h;
          VTl[((size_t)(bh8 + hh) * 16 + d) * 352 + kk] = l;
        }
      }
    }
  }
}

// ---------------- attention (R14 version): blocks [0,2048) = MFMA global
// attention, blocks [2048,2560) = local sliding-window (independent work).
// KH pads kk>=342 poison — safe (p forced to 0 by key<342 mask). VT rows
// n in [9,16) poison — safe (output columns discarded).
__global__ __launch_bounds__(256) void attn(
    const float* __restrict__ qkv_g, const float* __restrict__ qkv_l,
    const short* __restrict__ KH, const short* __restrict__ KL,
    const short* __restrict__ VTh, const short* __restrict__ VTl,
    float* __restrict__ o_g, float* __restrict__ pl, float* __restrict__ o_l)
{
  __shared__ short Pbuf[4][2][2][16][32];   // wave, parity, hi/lo, q, k
  const int u = blockIdx.x;
  if (u < 2048) {
    const int qt = u & 15, h = (u >> 4) & 7, b = u >> 7;
    const int w = threadIdx.x >> 6, lane = threadIdx.x & 63;
    const int quad = lane >> 4, r = lane & 15;
    const int bh = b * 8 + h;
    const int m0 = qt * 64 + w * 16;

    const short8 z8 = {0,0,0,0,0,0,0,0};
    short8 qh = z8, ql = z8;
    if (quad == 0) {
      const float* qp = qkv_g + (size_t)(b * 1024 + m0 + r) * 192 + h * 8;
      float4 a0 = ld4(qp), a1 = ld4(qp + 4);
      float qv[8] = {a0.x, a0.y, a0.z, a0.w, a1.x, a1.y, a1.z, a1.w};
      #pragma unroll
      for (int d = 0; d < 8; d++) { short hh, ll; bsplit(qv[d], hh, ll); qh[d]=hh; ql[d]=ll; }
    }
    const short* kbase  = KH + (size_t)bh * 2816;
    const short* klbase = KL + (size_t)bh * 2816;
    const short* vhbase = VTh + ((size_t)bh * 16 + r) * 352;
    const short* vlbase = VTl + ((size_t)bh * 16 + r) * 352;

    float4v oacc = {0.f, 0.f, 0.f, 0.f};

    for (int kc = 0; kc < 11; kc++) {
      short8 kh0 = z8, kl0 = z8, kh1 = z8, kl1 = z8;
      if (quad == 0) {
        kh0 = *(const short8*)(kbase  + (size_t)(kc * 32 + r) * 8);
        kl0 = *(const short8*)(klbase + (size_t)(kc * 32 + r) * 8);
        kh1 = *(const short8*)(kbase  + (size_t)(kc * 32 + 16 + r) * 8);
        kl1 = *(const short8*)(klbase + (size_t)(kc * 32 + 16 + r) * 8);
      }
      float4v s0 = {0.f,0.f,0.f,0.f}, s1 = {0.f,0.f,0.f,0.f};
      s0 = __builtin_amdgcn_mfma_f32_16x16x32_bf16(qh, kl0, s0, 0, 0, 0);
      s0 = __builtin_amdgcn_mfma_f32_16x16x32_bf16(ql, kh0, s0, 0, 0, 0);
      s0 = __builtin_amdgcn_mfma_f32_16x16x32_bf16(qh, kh0, s0, 0, 0, 0);
      s1 = __builtin_amdgcn_mfma_f32_16x16x32_bf16(qh, kl1, s1, 0, 0, 0);
      s1 = __builtin_amdgcn_mfma_f32_16x16x32_bf16(ql, kh1, s1, 0, 0, 0);
      s1 = __builtin_amdgcn_mfma_f32_16x16x32_bf16(qh, kh1, s1, 0, 0, 0);

      const int par = kc & 1;
      const int key0 = kc * 32 + r, key1 = key0 + 16;
      #pragma unroll
      for (int e = 0; e < 4; e++) {
        float p0 = (key0 < 342) ? __expf(s0[e] * INV_SQRT8) : 0.f;
        float p1 = (key1 < 342) ? __expf(s1[e] * INV_SQRT8) : 0.f;
        short h0, l0, h1, l1; bsplit(p0, h0, l0); bsplit(p1, h1, l1);
        const int qloc = quad * 4 + e;
        Pbuf[w][par][0][qloc][r]      = h0;
        Pbuf[w][par][0][qloc][16 + r] = h1;
        Pbuf[w][par][1][qloc][r]      = l0;
        Pbuf[w][par][1][qloc][16 + r] = l1;
      }
      // Same-wave LDS transpose read (DS ops in-order per wave; no barrier).
      short8 pA = *(const short8*)&Pbuf[w][par][0][r][quad * 8];
      short8 pB = *(const short8*)&Pbuf[w][par][1][r][quad * 8];
      short8 vh = *(const short8*)(vhbase + kc * 32 + quad * 8);
      short8 vl = *(const short8*)(vlbase + kc * 32 + quad * 8);
      oacc = __builtin_amdgcn_mfma_f32_16x16x32_bf16(pA, vl, oacc, 0, 0, 0);
      oacc = __builtin_amdgcn_mfma_f32_16x16x32_bf16(pB, vh, oacc, 0, 0, 0);
      oacc = __builtin_amdgcn_mfma_f32_16x16x32_bf16(pA, vh, oacc, 0, 0, 0);
    }

    #pragma unroll
    for (int e = 0; e < 4; e++) {
      const int orow = b * 1024 + m0 + quad * 4 + e;
      if (r < 8)       o_g[(size_t)orow * 64 + h * 8 + r] = oacc[e];
      else if (r == 8) pl[(size_t)orow * 8 + h] = oacc[e];
    }
  } else {
    int t = (u - 2048) * 256 + threadIdx.x;   // 131072
    int h = t & 7;
    int i = (t >> 3) & 1023;
    int b = t >> 13;
    const float* base = qkv_l + (size_t)b * 1024 * 192;
    const float* qp = base + (size_t)i * 192 + h * 8;
    float4 q0 = ld4(qp), q1 = ld4(qp + 4);
    float l = 0.f;
    float4 o0 = make_float4(0.f, 0.f, 0.f, 0.f);
    float4 o1 = make_float4(0.f, 0.f, 0.f, 0.f);
    int jlo = i - 5; if (jlo < 0) jlo = 0;
    int jhi = i + 5; if (jhi > 1023) jhi = 1023;
    for (int j = jlo; j <= jhi; j++) {
      const float* kp = base + (size_t)j * 192 + 64 + h * 8;
      float4 k0 = ld4(kp), k1 = ld4(kp + 4);
      float s = q0.x * k0.x + q0.y * k0.y + q0.z * k0.z + q0.w * k0.w
              + q1.x * k1.x + q1.y * k1.y + q1.z * k1.z + q1.w * k1.w;
      float p = __expf(s * INV_SQRT8);
      l += p;
      float4 v0 = ld4(kp + 64), v1 = ld4(kp + 68);
      o0 = f4fma(p, v0, o0);
      o1 = f4fma(p, v1, o1);
    }
    float inv = 1.f / l;
    float* op = o_l + (size_t)(b * 1024 + i) * 64 + h * 8;
    float4 r0, r1;
    r0.x = o0.x * inv; r0.y = o0.y * inv; r0.z = o0.z * inv; r0.w = o0.w * inv;
    r1.x = o1.x * inv; r1.y = o1.y * inv; r1.z = o1.z * inv; r1.w = o1.w * inv;
    *(float4*)op = r0;
    *(float4*)(op + 4) = r1;
  }
}

// ---------------- Fusion GEMM + score + pool partials (R14 version).
// Block = 64 rows (grid 256). Wave w: rows w*16..+16, ALL 64 cols (4 frags).
// Diag-key + 1/l normalization folded into A-load. Last block finalizes.
__global__ __launch_bounds__(256) void gemm_fuse_score(
    const float* __restrict__ o_l, const float* __restrict__ o_g,
    const float* __restrict__ pl, const float* __restrict__ qkv_g,
    const short* __restrict__ Wh, const short* __restrict__ Wl,
    const float* __restrict__ bc,
    const float* __restrict__ pw1, const float* __restrict__ pb1,
    const float* __restrict__ pw2, const float* __restrict__ pb2,
    float* __restrict__ num, float* __restrict__ den,
    unsigned* __restrict__ cnt, float* __restrict__ out)
{
  __shared__ float Ls[64][68];
  __shared__ float partial[4][64];
  __shared__ unsigned lastflag;
  const int tid = threadIdx.x;
  const int lane = tid & 63, w = tid >> 6;
  const int quad = lane >> 4, r = lane & 15;
  const int bx = blockIdx.x;
  const int m0 = bx * 64 + w * 16;

  float4v acc[4];
  #pragma unroll
  for (int g = 0; g < 4; g++) {
    float bv = bc[g * 16 + r];
    float4v t = {bv, bv, bv, bv};
    acc[g] = t;
  }

  #pragma unroll
  for (int ks = 0; ks < 4; ks++) {
    const int k0 = ks * 32 + quad * 8;
    const int row = m0 + r;
    float av[8];
    if (ks < 2) {   // local branch, already normalized
      const float* ap = o_l + (size_t)row * 64 + k0;
      float4 f0 = ld4(ap), f1 = ld4(ap + 4);
      av[0]=f0.x; av[1]=f0.y; av[2]=f0.z; av[3]=f0.w;
      av[4]=f1.x; av[5]=f1.y; av[6]=f1.z; av[7]=f1.w;
    } else {        // global branch: unnormalized O + diag + normalize
      const int off = k0 - 64;
      const int h = off >> 3;
      const float* op = o_g + (size_t)row * 64 + off;
      float4 O0 = ld4(op), O1 = ld4(op + 4);
      float l = pl[(size_t)row * 8 + h];
      const int i = row & 1023;
      if (i % 3 != 0) {
        const float* base = qkv_g + (size_t)row * 192;
        const float* qp = base + h * 8;
        const float* kpp = base + 64 + h * 8;
        const float* vp = base + 128 + h * 8;
        float4 q0 = ld4(qp), q1 = ld4(qp + 4);
        float4 k0v = ld4(kpp), k1v = ld4(kpp + 4);
        float s = q0.x*k0v.x + q0.y*k0v.y + q0.z*k0v.z + q0.w*k0v.w
                + q1.x*k1v.x + q1.y*k1v.y + q1.z*k1v.z + q1.w*k1v.w;
        float p = __expf(s * INV_SQRT8);
        float4 v0 = ld4(vp), v1 = ld4(vp + 4);
        O0 = f4fma(p, v0, O0); O1 = f4fma(p, v1, O1);
        l += p;
      }
      float inv = 1.f / l;
      av[0]=O0.x*inv; av[1]=O0.y*inv; av[2]=O0.z*inv; av[3]=O0.w*inv;
      av[4]=O1.x*inv; av[5]=O1.y*inv; av[6]=O1.z*inv; av[7]=O1.w*inv;
    }
    short8 ah, al;
    #pragma unroll
    for (int i2 = 0; i2 < 8; i2++) { short h2, l2; bsplit(av[i2], h2, l2); ah[i2]=h2; al[i2]=l2; }
    #pragma unroll
    for (int g = 0; g < 4; g++) {
      short8 bh = *(const short8*)(Wh + (size_t)(g * 16 + r) * 128 + k0);
      short8 bl = *(const short8*)(Wl + (size_t)(g * 16 + r) * 128 + k0);
      acc[g] = __builtin_amdgcn_mfma_f32_16x16x32_bf16(al, bh, acc[g], 0, 0, 0);
      acc[g] = __builtin_amdgcn_mfma_f32_16x16x32_bf16(ah, bl, acc[g], 0, 0, 0);
      acc[g] = __builtin_amdgcn_mfma_f32_16x16x32_bf16(ah, bh, acc[g], 0, 0, 0);
    }
  }

  // park C-tile in LDS: Ls[row_local][col]
  #pragma unroll
  for (int g = 0; g < 4; g++)
    #pragma unroll
    for (int e = 0; e < 4; e++)
      Ls[w * 16 + quad * 4 + e][g * 16 + r] = acc[g][e];
  __syncthreads();

  // score phase. lane = row_local.
  float4 fr[16];
  #pragma unroll
  for (int e = 0; e < 16; e++) fr[e] = *(float4*)&Ls[lane][e * 4];

  float psc = 0.f;
  #pragma unroll
  for (int jj = 0; jj < 8; jj++) {
    const int j = w * 8 + jj;
    const float* wr = pw1 + j * 64;   // wave-uniform -> s_load
    float hj = pb1[j];
    #pragma unroll
    for (int e = 0; e < 16; e++) {
      float4 wv = ld4(wr + e * 4);
      hj += fr[e].x * wv.x + fr[e].y * wv.y + fr[e].z * wv.z + fr[e].w * wv.w;
    }
    float e2 = __expf(2.f * hj);
    psc += ((e2 - 1.f) / (e2 + 1.f)) * pw2[j];   // tanh via exp
  }
  partial[w][lane] = psc;
  __syncthreads();
  if (w == 0) {
    const int b = bx >> 4;
    float sc = pb2[0] + partial[0][lane] + partial[1][lane]
             + partial[2][lane] + partial[3][lane];
    float p = __expf(sc);
    #pragma unroll
    for (int e = 0; e < 16; e++) {
      Ls[lane][e*4+0] = p * fr[e].x; Ls[lane][e*4+1] = p * fr[e].y;
      Ls[lane][e*4+2] = p * fr[e].z; Ls[lane][e*4+3] = p * fr[e].w;
    }
    // single wave: DS ops in order, no barrier needed
    float colsum = 0.f;
    #pragma unroll 8
    for (int s = 0; s < 64; s++) colsum += Ls[s][lane];
    atomicAdd(&num[b * 64 + lane], colsum);
    float ps = p;
    #pragma unroll
    for (int off = 32; off > 0; off >>= 1)
      ps += __shfl_xor(ps, off, 64);
    if (lane == 0) atomicAdd(&den[b], ps);
  }

  // ---- last-block finalize (replaces the finalize dispatch)
  if (tid == 0) {
    __threadfence();                       // release: num/den atomics visible
    lastflag = (atomicAdd(cnt, 1u) == 255u) ? 1u : 0u;
  }
  __syncthreads();
  if (lastflag) {
    __threadfence();                       // acquire side
    for (int k = tid; k < 1024; k += 256) {
      float nv = __hip_atomic_load(&num[k], __ATOMIC_RELAXED, __HIP_MEMORY_SCOPE_AGENT);
      float dv = __hip_atomic_load(&den[k >> 6], __ATOMIC_RELAXED, __HIP_MEMORY_SCOPE_AGENT);
      out[k] = nv / dv;
    }
  }
}

extern "C" void kernel_launch(void* const* d_in, const int* in_sizes, int n_in,
                              void* d_out, int out_size, void* d_ws, size_t ws_size,
                              hipStream_t stream)
{
  const float* x          = (const float*)d_in[0];
  const float* proj_w     = (const float*)d_in[1];
  const float* proj_b     = (const float*)d_in[2];
  const float* loc_in_w   = (const float*)d_in[3];
  const float* loc_in_b   = (const float*)d_in[4];
  const float* loc_out_w  = (const float*)d_in[5];
  const float* loc_out_b  = (const float*)d_in[6];
  const float* glob_in_w  = (const float*)d_in[7];
  const float* glob_in_b  = (const float*)d_in[8];
  const float* glob_out_w = (const float*)d_in[9];
  const float* glob_out_b = (const float*)d_in[10];
  const float* fusion_w   = (const float*)d_in[11];
  const float* fusion_b   = (const float*)d_in[12];
  const float* pw1        = (const float*)d_in[13];
  const float* pb1        = (const float*)d_in[14];
  const float* pw2        = (const float*)d_in[15];
  const float* pb2        = (const float*)d_in[16];

  float* ws = (float*)d_ws;
  // Layout (float offsets):
  //  qkv_g    [0, 3145728)
  //  qkv_l    [4587520, 7733248)
  //  o_l      [7733248, 8781824)
  //  o_g      [8781824, 9830400)
  //  pl       [9830400, 9961472)
  //  KH/KL    shorts at 9961472 / 10141696 (360448 each)
  //  VTh/VTl  shorts at 10321920 / 10682368 (720896 each)
  //  bc       [11042816, 11042880)
  //  num/den/cnt [11042880, 11043921)
  //  wb       shorts at 11043921+ (112640)
  float* qkv_g = ws;
  float* qkv_l = ws + 4587520;
  float* o_l   = ws + 7733248;
  float* o_g   = ws + 8781824;
  float* pl    = ws + 9830400;
  short* KH    = (short*)(ws + 9961472);
  short* KL    = (short*)(ws + 10141696);
  short* VTh   = (short*)(ws + 10321920);
  short* VTl   = (short*)(ws + 10682368);
  float* bc    = ws + 11042816;
  float* numden= ws + 11042880;
  float* num   = numden;
  float* den   = numden + 1024;
  unsigned* cnt= (unsigned*)(numden + 1040);
  short* wb    = (short*)(ws + 11043921);
  short* projh = wb;           short* projl = wb + 20480;
  short* linh  = wb + 40960;   short* linl  = wb + 53248;
  short* ginh  = wb + 65536;   short* ginl  = wb + 77824;
  short* wfh   = wb + 90112;   short* wfl   = wb + 98304;
  float* out   = (float*)d_out;

  dim3 blk(256);
  // 1: weight split + fused fusion weights + combined bias + zeros + VT pads
  //    idx range = 53248 + 55296 = 108544 = 424 * 256
  prep_w<<<424, blk, 0, stream>>>(proj_w, loc_in_w, glob_in_w, fusion_w,
                                  loc_out_w, glob_out_w, loc_out_b, glob_out_b,
                                  fusion_b, wb, bc, numden, VTh, VTl);
  // 2: fused proj + qkv GEMM; writes qkv_l, qkv_g, KH/KL, VTh/VTl
  gemm_proj_qkv<<<256, blk, 0, stream>>>(
      x, projh, projl, proj_b, linh, linl, ginh, ginl, loc_in_b, glob_in_b,
      qkv_l, qkv_g, KH, KL, VTh, VTl);
  // 3: global MFMA attention (2048 blocks) + local attention (512 blocks)
  attn<<<2560, blk, 0, stream>>>(qkv_g, qkv_l, KH, KL, VTh, VTl, o_g, pl, o_l);
  // 4: fusion GEMM + score + pool partials + last-block finalize
  gemm_fuse_score<<<256, blk, 0, stream>>>(
      o_l, o_g, pl, qkv_g, wfh, wfl, bc, pw1, pb1, pw2, pb2, num, den, cnt, out);
}